// Round 1
// baseline (480.775 us; speedup 1.0000x reference)
//
#include <hip/hip_runtime.h>
#include <cstddef>
#include <cstdint>

// Problem dims
#define T_DIM 4096
#define B_DIM 8
#define N_DIM 256
#define H_DIM 512
#define NT_DIM 5

typedef __attribute__((ext_vector_type(8))) short short8;   // 8 x bf16 bits (4 VGPR)
typedef __attribute__((ext_vector_type(4))) short short4v;  // 4 x bf16 bits
typedef __attribute__((ext_vector_type(4))) float f32x4;

__device__ inline short cvt_bf16(float f) {
  union { float f; uint32_t u; } v; v.f = f;
  uint32_t r = v.u + 0x7FFFu + ((v.u >> 16) & 1u);  // RNE
  return (short)(r >> 16);
}

// ---------------------------------------------------------------------------
// Generic TN GEMM: C[m,n] = scale * sum_k A[m,k] * Bt[n,k]  (+ Res[m,n])
// A: f32 (inline cvt) or bf16; Bt: bf16 with K contiguous; C: f32 or bf16.
// Tiles: 128x128 per block (256 thr = 4 waves, each wave 64x64 = 4x4 MFMA frags),
// BK=32. LDS rows padded to 40 elems -> only 2-way bank aliasing (free).
// M,N must be multiples of 128; K multiple of 32. Batch via blockIdx.z.
// ---------------------------------------------------------------------------
template<typename TA, typename TC, bool ADD_RES>
__global__ __launch_bounds__(256)
void gemm_tn(const TA* __restrict__ A, long long a_bs, int lda,
             const short* __restrict__ Bt, long long b_bs, int ldb,
             TC* __restrict__ C, long long c_bs, int ldc,
             const float* __restrict__ Res,
             int K, float scale) {
  constexpr int LDSK = 40;
  __shared__ short As[128 * LDSK];
  __shared__ short Bs[128 * LDSK];

  const int tid  = threadIdx.x;
  const int lane = tid & 63;
  const int wave = tid >> 6;
  const int wr   = (wave >> 1) * 64;
  const int wc   = (wave & 1) * 64;
  const int lrow = lane & 15;
  const int kgrp = lane >> 4;   // 0..3

  const long long zb = blockIdx.z;
  const TA*    Ab = A  + zb * a_bs + (long long)(blockIdx.x * 128) * lda;
  const short* Bb = Bt + zb * b_bs + (long long)(blockIdx.y * 128) * ldb;

  const int srow = tid >> 1;         // 0..127
  const int scol = (tid & 1) * 16;   // 0 or 16

  f32x4 acc[4][4] = {};

  for (int k0 = 0; k0 < K; k0 += 32) {
    __syncthreads();
    { // stage A (128x32)
      const TA* gp = Ab + (long long)srow * lda + k0 + scol;
      short8 s0, s1;
      if constexpr (sizeof(TA) == 4) {
        f32x4 v0 = *(const f32x4*)(gp + 0);
        f32x4 v1 = *(const f32x4*)(gp + 4);
        f32x4 v2 = *(const f32x4*)(gp + 8);
        f32x4 v3 = *(const f32x4*)(gp + 12);
        #pragma unroll
        for (int e = 0; e < 4; ++e) {
          s0[e]     = cvt_bf16(v0[e]);
          s0[4 + e] = cvt_bf16(v1[e]);
          s1[e]     = cvt_bf16(v2[e]);
          s1[4 + e] = cvt_bf16(v3[e]);
        }
      } else {
        s0 = *(const short8*)((const short*)gp);
        s1 = *(const short8*)((const short*)gp + 8);
      }
      *(short8*)&As[srow * LDSK + scol]     = s0;
      *(short8*)&As[srow * LDSK + scol + 8] = s1;
    }
    { // stage B (128 n-rows x 32 k)
      const short* gp = Bb + (long long)srow * ldb + k0 + scol;
      short8 s0 = *(const short8*)(gp);
      short8 s1 = *(const short8*)(gp + 8);
      *(short8*)&Bs[srow * LDSK + scol]     = s0;
      *(short8*)&Bs[srow * LDSK + scol + 8] = s1;
    }
    __syncthreads();

    short8 af[4], bfr[4];
    #pragma unroll
    for (int i = 0; i < 4; ++i)
      af[i] = *(const short8*)&As[(wr + i * 16 + lrow) * LDSK + kgrp * 8];
    #pragma unroll
    for (int j = 0; j < 4; ++j)
      bfr[j] = *(const short8*)&Bs[(wc + j * 16 + lrow) * LDSK + kgrp * 8];
    #pragma unroll
    for (int i = 0; i < 4; ++i)
      #pragma unroll
      for (int j = 0; j < 4; ++j)
        acc[i][j] = __builtin_amdgcn_mfma_f32_16x16x32_bf16(af[i], bfr[j], acc[i][j], 0, 0, 0);
  }

  // epilogue: D layout col=lane&15, row=(lane>>4)*4+r  [m89-verified]
  const long long cb = zb * c_bs;
  const int gm = blockIdx.x * 128 + wr;
  const int gn = blockIdx.y * 128 + wc;
  #pragma unroll
  for (int i = 0; i < 4; ++i) {
    #pragma unroll
    for (int j = 0; j < 4; ++j) {
      const int col = gn + j * 16 + lrow;
      #pragma unroll
      for (int r = 0; r < 4; ++r) {
        const int row = gm + i * 16 + kgrp * 4 + r;
        const long long idx = cb + (long long)row * ldc + col;
        float v = acc[i][j][r] * scale;
        if constexpr (ADD_RES) v += Res[idx];
        if constexpr (sizeof(TC) == 2) C[idx] = cvt_bf16(v);
        else                           C[idx] = v;
      }
    }
  }
}

// ---------------------------------------------------------------------------
// Weight transpose + f32->bf16: WT[n][k] = bf16(W[k][n]), 8 matrices of 512x512
// ---------------------------------------------------------------------------
struct WSrc { const float* p[8]; };

__global__ __launch_bounds__(256)
void wtrans_kernel(WSrc s, short* __restrict__ dst) {
  __shared__ float tile[32][33];
  const int w = blockIdx.z;
  const float* src = s.p[w];
  short* d = dst + (long long)w * H_DIM * H_DIM;
  const int tx = threadIdx.x, ty = threadIdx.y;
  const int n0 = blockIdx.x * 32, k0 = blockIdx.y * 32;
  #pragma unroll
  for (int i = 0; i < 4; ++i)
    tile[ty + 8 * i][tx] = src[(long long)(k0 + ty + 8 * i) * H_DIM + n0 + tx];
  __syncthreads();
  #pragma unroll
  for (int i = 0; i < 4; ++i)
    d[(long long)(n0 + ty + 8 * i) * H_DIM + k0 + tx] = cvt_bf16(tile[tx][ty + 8 * i]);
}

// ---------------------------------------------------------------------------
// V transpose (bf16): VT[b][h][n] = V[n][b][h], per domain, batch z = dom*8+b
// ---------------------------------------------------------------------------
__global__ __launch_bounds__(256)
void vtrans_kernel(const short* __restrict__ Vv, const short* __restrict__ Vt,
                   short* __restrict__ VTv, short* __restrict__ VTt) {
  __shared__ short tile[32][33];
  const int z = blockIdx.z;
  const int dom = z >> 3, b = z & 7;
  const short* src = dom ? Vt : Vv;
  short* dst = dom ? VTt : VTv;
  const int tx = threadIdx.x, ty = threadIdx.y;
  const int h0 = blockIdx.x * 32, n0 = blockIdx.y * 32;
  #pragma unroll
  for (int i = 0; i < 4; ++i)
    tile[ty + 8 * i][tx] =
        src[(long long)(n0 + ty + 8 * i) * (B_DIM * H_DIM) + b * H_DIM + h0 + tx];
  __syncthreads();
  #pragma unroll
  for (int i = 0; i < 4; ++i)
    dst[(long long)b * H_DIM * N_DIM + (long long)(h0 + ty + 8 * i) * N_DIM + n0 + tx] =
        tile[tx][ty + 8 * i];
}

// ---------------------------------------------------------------------------
// Cross-domain combine + masked softmax (both domains).
// Reads logits Lv,Lt [B,T,N] f32; writes combined in-place (nomask values) and
// bf16 attention Av,At [B,T,N]. One wave per row; 4 rows/wave; grid(T/16, B).
// ---------------------------------------------------------------------------
__global__ __launch_bounds__(256)
void softmax_kernel(float* __restrict__ Lv, float* __restrict__ Lt,
                    const int* __restrict__ vmask, const int* __restrict__ tmask,
                    const float* __restrict__ vaw, const float* __restrict__ taw,
                    short* __restrict__ Av, short* __restrict__ At) {
  const int tid  = threadIdx.x;
  const int lane = tid & 63;
  const int wave = tid >> 6;
  const int b    = blockIdx.y;
  const float sv = 1.f / (1.f + __expf(-vaw[0]));
  const float st = 1.f / (1.f + __expf(-taw[0]));
  const int4 mv4 = *(const int4*)&vmask[b * N_DIM + lane * 4];
  const int4 mt4 = *(const int4*)&tmask[b * N_DIM + lane * 4];
  const int mv[4] = {mv4.x, mv4.y, mv4.z, mv4.w};
  const int mt[4] = {mt4.x, mt4.y, mt4.z, mt4.w};
  const float NEG = -__builtin_inff();

  #pragma unroll
  for (int r = 0; r < 4; ++r) {
    const int t = blockIdx.x * 16 + wave * 4 + r;
    const long long off = ((long long)b * T_DIM + t) * N_DIM + lane * 4;
    f32x4 lv = *(const f32x4*)&Lv[off];
    f32x4 lt = *(const f32x4*)&Lt[off];
    f32x4 cv, ct;
    #pragma unroll
    for (int e = 0; e < 4; ++e) {
      cv[e] = lv[e] + sv * lt[e];
      ct[e] = lt[e] + st * lv[e];
    }
    *(f32x4*)&Lv[off] = cv;   // nomask (pre-mask combined)
    *(f32x4*)&Lt[off] = ct;

    { // v softmax
      float m = NEG;
      #pragma unroll
      for (int e = 0; e < 4; ++e) if (mv[e] > 0) m = fmaxf(m, cv[e]);
      #pragma unroll
      for (int sh = 32; sh > 0; sh >>= 1) m = fmaxf(m, __shfl_xor(m, sh));
      float ev[4]; float sum = 0.f;
      #pragma unroll
      for (int e = 0; e < 4; ++e) {
        ev[e] = (mv[e] > 0) ? __expf(cv[e] - m) : 0.f;
        sum += ev[e];
      }
      #pragma unroll
      for (int sh = 32; sh > 0; sh >>= 1) sum += __shfl_xor(sum, sh);
      const float inv = 1.f / sum;
      short4v o;
      #pragma unroll
      for (int e = 0; e < 4; ++e) o[e] = cvt_bf16(ev[e] * inv);
      *(short4v*)&Av[off] = o;
    }
    { // t softmax
      float m = NEG;
      #pragma unroll
      for (int e = 0; e < 4; ++e) if (mt[e] > 0) m = fmaxf(m, ct[e]);
      #pragma unroll
      for (int sh = 32; sh > 0; sh >>= 1) m = fmaxf(m, __shfl_xor(m, sh));
      float ev[4]; float sum = 0.f;
      #pragma unroll
      for (int e = 0; e < 4; ++e) {
        ev[e] = (mt[e] > 0) ? __expf(ct[e] - m) : 0.f;
        sum += ev[e];
      }
      #pragma unroll
      for (int sh = 32; sh > 0; sh >>= 1) sum += __shfl_xor(sum, sh);
      const float inv = 1.f / sum;
      short4v o;
      #pragma unroll
      for (int e = 0; e < 4; ++e) o[e] = cvt_bf16(ev[e] * inv);
      *(short4v*)&At[off] = o;
    }
  }
}

// ---------------------------------------------------------------------------
// nomask transpose: [B,T,N] f32 -> [B,N,T] f32 into d_out. z = dom*8+b.
// ---------------------------------------------------------------------------
__global__ __launch_bounds__(256)
void nmtrans_kernel(const float* __restrict__ Lv, const float* __restrict__ Lt,
                    float* __restrict__ Ov, float* __restrict__ Ot) {
  __shared__ float tile[32][33];
  const int z = blockIdx.z;
  const int dom = z >> 3, b = z & 7;
  const float* src = (dom ? Lt : Lv) + (long long)b * T_DIM * N_DIM;
  float* dst = (dom ? Ot : Ov) + (long long)b * N_DIM * T_DIM;
  const int tx = threadIdx.x, ty = threadIdx.y;
  const int t0 = blockIdx.x * 32, n0 = blockIdx.y * 32;
  #pragma unroll
  for (int i = 0; i < 4; ++i)
    tile[ty + 8 * i][tx] = src[(long long)(t0 + ty + 8 * i) * N_DIM + n0 + tx];
  __syncthreads();
  #pragma unroll
  for (int i = 0; i < 4; ++i)
    dst[(long long)(n0 + ty + 8 * i) * T_DIM + t0 + tx] = tile[tx][ty + 8 * i];
}

// ---------------------------------------------------------------------------
// Task heads: ta[k,b] = dot(task[k,b,:], tw) + tb  (both domains; 80 dots)
// ---------------------------------------------------------------------------
__global__ __launch_bounds__(1024)
void task_kernel(const float* __restrict__ vtask, const float* __restrict__ ttask,
                 const float* __restrict__ vtw, const float* __restrict__ vtb,
                 const float* __restrict__ ttw, const float* __restrict__ ttb,
                 float* __restrict__ out_v, float* __restrict__ out_t) {
  const int wave = threadIdx.x >> 6;
  const int lane = threadIdx.x & 63;
  const int dom = wave >> 3;
  const int b   = wave & 7;
  const float* task = dom ? ttask : vtask;
  const float* tw   = dom ? ttw : vtw;
  const float  tb   = (dom ? ttb : vtb)[0];
  float* o = dom ? out_t : out_v;
  for (int k = 0; k < NT_DIM; ++k) {
    const float* row = task + ((long long)k * B_DIM + b) * H_DIM;
    float s = 0.f;
    for (int c = lane; c < H_DIM; c += 64) s += row[c] * tw[c];
    #pragma unroll
    for (int d = 32; d > 0; d >>= 1) s += __shfl_xor(s, d);
    if (lane == 0) o[k * B_DIM + b] = s + tb;
  }
}

// ---------------------------------------------------------------------------
extern "C" void kernel_launch(void* const* d_in, const int* in_sizes, int n_in,
                              void* d_out, int out_size, void* d_ws, size_t ws_size,
                              hipStream_t stream) {
  const float* v_action = (const float*)d_in[0];
  const float* v_frame  = (const float*)d_in[1];
  const float* v_task   = (const float*)d_in[2];
  const int*   v_mask   = (const int*)d_in[3];
  const float* t_action = (const float*)d_in[4];
  const float* t_frame  = (const float*)d_in[5];
  const float* t_task   = (const float*)d_in[6];
  const int*   t_mask   = (const int*)d_in[7];
  const float* v_aw = (const float*)d_in[16];
  const float* t_aw = (const float*)d_in[17];
  const float* v_tw = (const float*)d_in[18];
  const float* v_tb = (const float*)d_in[19];
  const float* t_tw = (const float*)d_in[20];
  const float* t_tb = (const float*)d_in[21];

  const long long TBH = (long long)T_DIM * B_DIM * H_DIM;  // 16,777,216
  const long long BTN = (long long)B_DIM * T_DIM * N_DIM;  //  8,388,608
  const long long NBH = (long long)N_DIM * B_DIM * H_DIM;  //  1,048,576
  const long long WS  = (long long)H_DIM * H_DIM;          //    262,144

  float* out = (float*)d_out;
  float* out_v   = out;
  float* out_t   = out + TBH;
  float* out_vnm = out + 2 * TBH;
  float* out_tnm = out + 2 * TBH + BTN;
  float* out_vta = out + 2 * TBH + 2 * BTN;
  float* out_tta = out_vta + NT_DIM * B_DIM;

  // workspace layout (~185 MB)
  char* w = (char*)d_ws;
  auto alloc = [&](long long bytes) {
    char* p = w; w += (bytes + 255) & ~255LL; return p;
  };
  short* WT  = (short*)alloc(8 * WS * 2);   // 8 transposed bf16 weights
  short* Qv  = (short*)alloc(TBH * 2);      // reused as midv
  short* Qt  = (short*)alloc(TBH * 2);      // reused as midt
  short* Kv  = (short*)alloc(NBH * 2);
  short* Kt  = (short*)alloc(NBH * 2);
  short* Vv  = (short*)alloc(NBH * 2);
  short* Vt  = (short*)alloc(NBH * 2);
  short* VTv = (short*)alloc(NBH * 2);
  short* VTt = (short*)alloc(NBH * 2);
  short* Av  = (short*)alloc(BTN * 2);
  short* At  = (short*)alloc(BTN * 2);
  float* Lv  = (float*)alloc(BTN * 4);
  float* Lt  = (float*)alloc(BTN * 4);
  short* midv = Qv;
  short* midt = Qt;

  const float rsq = 0.044194173824159216f;  // 1/sqrt(512)

  // 1. transpose+convert the 8 weight matrices
  WSrc ws8;
  for (int i = 0; i < 8; ++i) ws8.p[i] = (const float*)d_in[8 + i];
  wtrans_kernel<<<dim3(16, 16, 8), dim3(32, 8), 0, stream>>>(ws8, WT);

  // 2. projections (A f32 -> C bf16)
  gemm_tn<float, short, false><<<dim3(256, 4, 1), dim3(256), 0, stream>>>(
      v_frame, 0LL, H_DIM, WT + 0 * WS, 0LL, H_DIM, Qv, 0LL, H_DIM, nullptr, 512, 1.f);
  gemm_tn<float, short, false><<<dim3(256, 4, 1), dim3(256), 0, stream>>>(
      t_frame, 0LL, H_DIM, WT + 4 * WS, 0LL, H_DIM, Qt, 0LL, H_DIM, nullptr, 512, 1.f);
  gemm_tn<float, short, false><<<dim3(16, 4, 1), dim3(256), 0, stream>>>(
      v_action, 0LL, H_DIM, WT + 1 * WS, 0LL, H_DIM, Kv, 0LL, H_DIM, nullptr, 512, 1.f);
  gemm_tn<float, short, false><<<dim3(16, 4, 1), dim3(256), 0, stream>>>(
      t_action, 0LL, H_DIM, WT + 5 * WS, 0LL, H_DIM, Kt, 0LL, H_DIM, nullptr, 512, 1.f);
  gemm_tn<float, short, false><<<dim3(16, 4, 1), dim3(256), 0, stream>>>(
      v_action, 0LL, H_DIM, WT + 2 * WS, 0LL, H_DIM, Vv, 0LL, H_DIM, nullptr, 512, 1.f);
  gemm_tn<float, short, false><<<dim3(16, 4, 1), dim3(256), 0, stream>>>(
      t_action, 0LL, H_DIM, WT + 6 * WS, 0LL, H_DIM, Vt, 0LL, H_DIM, nullptr, 512, 1.f);

  // 3. V transpose -> VT[b][h][n]
  vtrans_kernel<<<dim3(16, 8, 16), dim3(32, 8), 0, stream>>>(Vv, Vt, VTv, VTt);

  // 4. logits [B,T,N] = Q . K^T / sqrt(H), batched over b
  gemm_tn<short, float, false><<<dim3(32, 2, 8), dim3(256), 0, stream>>>(
      Qv, (long long)H_DIM, B_DIM * H_DIM, Kv, (long long)H_DIM, B_DIM * H_DIM,
      Lv, (long long)T_DIM * N_DIM, N_DIM, nullptr, 512, rsq);
  gemm_tn<short, float, false><<<dim3(32, 2, 8), dim3(256), 0, stream>>>(
      Qt, (long long)H_DIM, B_DIM * H_DIM, Kt, (long long)H_DIM, B_DIM * H_DIM,
      Lt, (long long)T_DIM * N_DIM, N_DIM, nullptr, 512, rsq);

  // 5. combine + masked softmax (both domains), in-place combined + bf16 attn
  softmax_kernel<<<dim3(T_DIM / 16, B_DIM), dim3(256), 0, stream>>>(
      Lv, Lt, v_mask, t_mask, v_aw, t_aw, Av, At);

  // 6. nomask transposed outputs [B,N,T]
  nmtrans_kernel<<<dim3(T_DIM / 32, N_DIM / 32, 16), dim3(32, 8), 0, stream>>>(
      Lv, Lt, out_vnm, out_tnm);

  // 7. mid[t,b,h] = attn @ V, batched over b
  gemm_tn<short, short, false><<<dim3(32, 4, 8), dim3(256), 0, stream>>>(
      Av, (long long)T_DIM * N_DIM, N_DIM, VTv, (long long)H_DIM * N_DIM, N_DIM,
      midv, (long long)H_DIM, B_DIM * H_DIM, nullptr, 256, 1.f);
  gemm_tn<short, short, false><<<dim3(32, 4, 8), dim3(256), 0, stream>>>(
      At, (long long)T_DIM * N_DIM, N_DIM, VTt, (long long)H_DIM * N_DIM, N_DIM,
      midt, (long long)H_DIM, B_DIM * H_DIM, nullptr, 256, 1.f);

  // 8. final = mid @ Wo + frame  -> d_out (f32)
  gemm_tn<short, float, true><<<dim3(256, 4, 1), dim3(256), 0, stream>>>(
      midv, 0LL, H_DIM, WT + 3 * WS, 0LL, H_DIM, out_v, 0LL, H_DIM, v_frame, 512, 1.f);
  gemm_tn<short, float, true><<<dim3(256, 4, 1), dim3(256), 0, stream>>>(
      midt, 0LL, H_DIM, WT + 7 * WS, 0LL, H_DIM, out_t, 0LL, H_DIM, t_frame, 512, 1.f);

  // 9. task heads
  task_kernel<<<dim3(1), dim3(1024), 0, stream>>>(
      v_task, t_task, v_tw, v_tb, t_tw, t_tb, out_vta, out_tta);
}

// Round 2
// 441.889 us; speedup vs baseline: 1.0880x; 1.0880x over previous
//
#include <hip/hip_runtime.h>
#include <cstddef>
#include <cstdint>

#define T_DIM 4096
#define B_DIM 8
#define N_DIM 256
#define H_DIM 512
#define NT_DIM 5

typedef __attribute__((ext_vector_type(8))) short short8;
typedef __attribute__((ext_vector_type(4))) short short4v;
typedef __attribute__((ext_vector_type(4))) float f32x4;

__device__ __forceinline__ short cvt_bf16(float f) {
  union { float f; uint32_t u; } v; v.f = f;
  uint32_t r = v.u + 0x7FFFu + ((v.u >> 16) & 1u);  // RNE
  return (short)(r >> 16);
}
__device__ __forceinline__ float bf2f(short s) {
  union { uint32_t u; float f; } v; v.u = ((uint32_t)(uint16_t)s) << 16;
  return v.f;
}

// async global->LDS, 16B per lane; LDS dest = wave-uniform base + lane*16
typedef __attribute__((address_space(1))) const void gvoid_t;
typedef __attribute__((address_space(3))) void lvoid_t;
__device__ __forceinline__ void gl_lds16(const void* g, void* lds_wave_base) {
  __builtin_amdgcn_global_load_lds((gvoid_t*)(uintptr_t)g,
                                   (lvoid_t*)(uint32_t)(uintptr_t)lds_wave_base,
                                   16, 0, 0);
}

// ---------------------------------------------------------------------------
// TN GEMM: C[m,n] = scale * sum_k A[m,k] * Bt[n,k]  (+ Res[m,n])
// 128x128 tile, 4 waves, BK=32, 16x16x32 bf16 MFMA.
// B staged via global_load_lds (linear LDS [128][32]).
// A: bf16 -> global_load_lds; f32 -> reg-staged cvt into padded LDS [128][40].
// ---------------------------------------------------------------------------
template<typename TA, typename TC, bool ADD_RES>
__global__ __launch_bounds__(256)
void gemm_tn(const TA* __restrict__ A, long long a_bs, int lda,
             const short* __restrict__ Bt, long long b_bs, int ldb,
             TC* __restrict__ C, long long c_bs, int ldc,
             const float* __restrict__ Res,
             int K, float scale) {
  constexpr int AS_STRIDE = (sizeof(TA) == 4) ? 40 : 32;
  __shared__ short As[128 * AS_STRIDE];
  __shared__ short Bs[128 * 32];

  const int tid  = threadIdx.x;
  const int lane = tid & 63;
  const int wave = tid >> 6;
  const int wr   = (wave >> 1) * 64;
  const int wc   = (wave & 1) * 64;
  const int lrow = lane & 15;
  const int kgrp = lane >> 4;

  const long long zb = blockIdx.z;
  const TA*    Ab = A  + zb * a_bs + (long long)(blockIdx.x * 128) * lda;
  const short* Bb = Bt + zb * b_bs + (long long)(blockIdx.y * 128) * ldb;

  // lds-direct chunk geometry: chunk c covers rows c*16..c*16+15 (1 KiB)
  const int ch_r = lane >> 2;        // row within chunk
  const int ch_c = (lane & 3) * 8;   // col (shorts)
  // f32 reg-stage geometry
  const int srow = tid >> 1;
  const int scol = (tid & 1) * 16;

  f32x4 acc[4][4] = {};

  for (int k0 = 0; k0 < K; k0 += 32) {
    __syncthreads();
    if constexpr (sizeof(TA) == 4) {
      const TA* gp = Ab + (long long)srow * lda + k0 + scol;
      f32x4 v0 = *(const f32x4*)(gp + 0);
      f32x4 v1 = *(const f32x4*)(gp + 4);
      f32x4 v2 = *(const f32x4*)(gp + 8);
      f32x4 v3 = *(const f32x4*)(gp + 12);
      short8 s0, s1;
      #pragma unroll
      for (int e = 0; e < 4; ++e) {
        s0[e]     = cvt_bf16(v0[e]);
        s0[4 + e] = cvt_bf16(v1[e]);
        s1[e]     = cvt_bf16(v2[e]);
        s1[4 + e] = cvt_bf16(v3[e]);
      }
      *(short8*)&As[srow * AS_STRIDE + scol]     = s0;
      *(short8*)&As[srow * AS_STRIDE + scol + 8] = s1;
    } else {
      #pragma unroll
      for (int i = 0; i < 2; ++i) {
        const int c = wave + 4 * i;
        gl_lds16(Ab + (long long)(c * 16 + ch_r) * lda + k0 + ch_c, &As[c * 512]);
      }
    }
    #pragma unroll
    for (int i = 0; i < 2; ++i) {
      const int c = wave + 4 * i;
      gl_lds16(Bb + (long long)(c * 16 + ch_r) * ldb + k0 + ch_c, &Bs[c * 512]);
    }
    __syncthreads();

    short8 af[4], bfr[4];
    #pragma unroll
    for (int i = 0; i < 4; ++i)
      af[i] = *(const short8*)&As[(wr + i * 16 + lrow) * AS_STRIDE + kgrp * 8];
    #pragma unroll
    for (int j = 0; j < 4; ++j)
      bfr[j] = *(const short8*)&Bs[(wc + j * 16 + lrow) * 32 + kgrp * 8];
    #pragma unroll
    for (int i = 0; i < 4; ++i)
      #pragma unroll
      for (int j = 0; j < 4; ++j)
        acc[i][j] = __builtin_amdgcn_mfma_f32_16x16x32_bf16(af[i], bfr[j], acc[i][j], 0, 0, 0);
  }

  const long long cb = zb * c_bs;
  const int gm = blockIdx.x * 128 + wr;
  const int gn = blockIdx.y * 128 + wc;
  #pragma unroll
  for (int i = 0; i < 4; ++i) {
    #pragma unroll
    for (int j = 0; j < 4; ++j) {
      const int col = gn + j * 16 + lrow;
      #pragma unroll
      for (int r = 0; r < 4; ++r) {
        const int row = gm + i * 16 + kgrp * 4 + r;
        const long long idx = cb + (long long)row * ldc + col;
        float v = acc[i][j][r] * scale;
        if constexpr (ADD_RES) v += Res[idx];
        if constexpr (sizeof(TC) == 2) C[idx] = cvt_bf16(v);
        else                           C[idx] = v;
      }
    }
  }
}

// ---------------------------------------------------------------------------
// Weight transpose + cvt: WT[w][n][k] = bf16(W[w][k][n]), 8 matrices 512x512
// ---------------------------------------------------------------------------
struct WSrc { const float* p[8]; };

__global__ __launch_bounds__(256)
void wtrans_kernel(WSrc s, short* __restrict__ dst) {
  __shared__ float tile[32][33];
  const int w = blockIdx.z;
  const float* src = s.p[w];
  short* d = dst + (long long)w * H_DIM * H_DIM;
  const int tx = threadIdx.x, ty = threadIdx.y;
  const int n0 = blockIdx.x * 32, k0 = blockIdx.y * 32;
  #pragma unroll
  for (int i = 0; i < 4; ++i)
    tile[ty + 8 * i][tx] = src[(long long)(k0 + ty + 8 * i) * H_DIM + n0 + tx];
  __syncthreads();
  #pragma unroll
  for (int i = 0; i < 4; ++i)
    d[(long long)(n0 + ty + 8 * i) * H_DIM + k0 + tx] = cvt_bf16(tile[tx][ty + 8 * i]);
}

// ---------------------------------------------------------------------------
// V transpose from merged KV: VT[b][h][n] = KV[(n*8+b)*1024 + 512 + h]
// ---------------------------------------------------------------------------
__global__ __launch_bounds__(256)
void vtrans_kernel(const short* __restrict__ KVv, const short* __restrict__ KVt,
                   short* __restrict__ VTv, short* __restrict__ VTt) {
  __shared__ short tile[32][33];
  const int z = blockIdx.z;
  const int dom = z >> 3, b = z & 7;
  const short* src = (dom ? KVt : KVv) + b * 1024 + 512;
  short* dst = (dom ? VTt : VTv) + (long long)b * H_DIM * N_DIM;
  const int tx = threadIdx.x, ty = threadIdx.y;
  const int h0 = blockIdx.x * 32, n0 = blockIdx.y * 32;
  #pragma unroll
  for (int i = 0; i < 4; ++i)
    tile[ty + 8 * i][tx] = src[(long long)(n0 + ty + 8 * i) * 8192 + h0 + tx];
  __syncthreads();
  #pragma unroll
  for (int i = 0; i < 4; ++i)
    dst[(long long)(h0 + ty + 8 * i) * N_DIM + n0 + tx] = tile[tx][ty + 8 * i];
}

// ---------------------------------------------------------------------------
// Fused: combine + masked softmax + bf16 attn + nomask transpose to d_out.
// Grid (T/16, B), 256 thr. r=tid>>4 (t-row), seg=tid&15 (16-col slice).
// ---------------------------------------------------------------------------
__global__ __launch_bounds__(256)
void softmax_fused(const short* __restrict__ Lv, const short* __restrict__ Lt,
                   const int* __restrict__ vmask, const int* __restrict__ tmask,
                   const float* __restrict__ vaw, const float* __restrict__ taw,
                   short* __restrict__ Av, short* __restrict__ At,
                   float* __restrict__ Onm_v, float* __restrict__ Onm_t) {
  __shared__ float tile[16 * 260];
  __shared__ int msk[2][256];
  const int tid = threadIdx.x;
  const int b = blockIdx.y, t0 = blockIdx.x * 16;
  const int r = tid >> 4, seg = tid & 15;
  msk[0][tid] = vmask[b * 256 + tid];
  msk[1][tid] = tmask[b * 256 + tid];
  __syncthreads();
  const float sv = 1.f / (1.f + __expf(-vaw[0]));
  const float st = 1.f / (1.f + __expf(-taw[0]));
  const long long off = ((long long)b * T_DIM + t0 + r) * N_DIM + seg * 16;

  short8 lv0 = *(const short8*)&Lv[off];
  short8 lv1 = *(const short8*)&Lv[off + 8];
  short8 lt0 = *(const short8*)&Lt[off];
  short8 lt1 = *(const short8*)&Lt[off + 8];
  float cv[16], ct[16];
  #pragma unroll
  for (int i = 0; i < 8; ++i) {
    float a0 = bf2f(lv0[i]), b0 = bf2f(lt0[i]);
    float a1 = bf2f(lv1[i]), b1 = bf2f(lt1[i]);
    cv[i]     = a0 + sv * b0;  ct[i]     = b0 + st * a0;
    cv[8 + i] = a1 + sv * b1;  ct[8 + i] = b1 + st * a1;
  }

#define EMIT_DOMAIN(CVAL, DI, AOUT, ONM) do {                                   \
    const int4 mA = *(const int4*)&msk[DI][seg * 16 + 0];                       \
    const int4 mB = *(const int4*)&msk[DI][seg * 16 + 4];                       \
    const int4 mC = *(const int4*)&msk[DI][seg * 16 + 8];                       \
    const int4 mD = *(const int4*)&msk[DI][seg * 16 + 12];                      \
    const int mk[16] = {mA.x, mA.y, mA.z, mA.w, mB.x, mB.y, mB.z, mB.w,         \
                        mC.x, mC.y, mC.z, mC.w, mD.x, mD.y, mD.z, mD.w};        \
    float mx = -3.4e38f;                                                        \
    _Pragma("unroll")                                                           \
    for (int q = 0; q < 16; ++q) if (mk[q] > 0) mx = fmaxf(mx, CVAL[q]);        \
    _Pragma("unroll")                                                           \
    for (int sh = 1; sh < 16; sh <<= 1) mx = fmaxf(mx, __shfl_xor(mx, sh));     \
    float ev[16]; float ssum = 0.f;                                             \
    _Pragma("unroll")                                                           \
    for (int q = 0; q < 16; ++q) {                                              \
      ev[q] = (mk[q] > 0) ? __expf(CVAL[q] - mx) : 0.f; ssum += ev[q];          \
    }                                                                           \
    _Pragma("unroll")                                                           \
    for (int sh = 1; sh < 16; sh <<= 1) ssum += __shfl_xor(ssum, sh);           \
    const float inv = 1.f / ssum;                                               \
    short8 o0, o1;                                                              \
    _Pragma("unroll")                                                           \
    for (int q = 0; q < 8; ++q) {                                               \
      o0[q] = cvt_bf16(ev[q] * inv); o1[q] = cvt_bf16(ev[8 + q] * inv);         \
    }                                                                           \
    *(short8*)&AOUT[off] = o0; *(short8*)&AOUT[off + 8] = o1;                   \
    _Pragma("unroll")                                                           \
    for (int q = 0; q < 4; ++q) {                                               \
      f32x4 tv; tv[0] = CVAL[q * 4]; tv[1] = CVAL[q * 4 + 1];                   \
      tv[2] = CVAL[q * 4 + 2]; tv[3] = CVAL[q * 4 + 3];                         \
      *(f32x4*)&tile[r * 260 + seg * 16 + q * 4] = tv;                          \
    }                                                                           \
    __syncthreads();                                                            \
    {                                                                           \
      float* obase = &ONM[((long long)b * N_DIM + tid) * T_DIM + t0];           \
      _Pragma("unroll")                                                         \
      for (int g = 0; g < 4; ++g) {                                             \
        f32x4 wv;                                                               \
        wv[0] = tile[(4 * g + 0) * 260 + tid];                                  \
        wv[1] = tile[(4 * g + 1) * 260 + tid];                                  \
        wv[2] = tile[(4 * g + 2) * 260 + tid];                                  \
        wv[3] = tile[(4 * g + 3) * 260 + tid];                                  \
        *(f32x4*)&obase[4 * g] = wv;                                            \
      }                                                                         \
    }                                                                           \
    __syncthreads();                                                            \
  } while (0)

  EMIT_DOMAIN(cv, 0, Av, Onm_v);
  EMIT_DOMAIN(ct, 1, At, Onm_t);
#undef EMIT_DOMAIN
}

// ---------------------------------------------------------------------------
// Task heads
// ---------------------------------------------------------------------------
__global__ __launch_bounds__(1024)
void task_kernel(const float* __restrict__ vtask, const float* __restrict__ ttask,
                 const float* __restrict__ vtw, const float* __restrict__ vtb,
                 const float* __restrict__ ttw, const float* __restrict__ ttb,
                 float* __restrict__ out_v, float* __restrict__ out_t) {
  const int wave = threadIdx.x >> 6;
  const int lane = threadIdx.x & 63;
  const int dom = wave >> 3;
  const int b   = wave & 7;
  const float* task = dom ? ttask : vtask;
  const float* tw   = dom ? ttw : vtw;
  const float  tb   = (dom ? ttb : vtb)[0];
  float* o = dom ? out_t : out_v;
  for (int k = 0; k < NT_DIM; ++k) {
    const float* row = task + ((long long)k * B_DIM + b) * H_DIM;
    float s = 0.f;
    for (int c = lane; c < H_DIM; c += 64) s += row[c] * tw[c];
    #pragma unroll
    for (int d = 32; d > 0; d >>= 1) s += __shfl_xor(s, d);
    if (lane == 0) o[k * B_DIM + b] = s + tb;
  }
}

// ---------------------------------------------------------------------------
extern "C" void kernel_launch(void* const* d_in, const int* in_sizes, int n_in,
                              void* d_out, int out_size, void* d_ws, size_t ws_size,
                              hipStream_t stream) {
  const float* v_action = (const float*)d_in[0];
  const float* v_frame  = (const float*)d_in[1];
  const float* v_task   = (const float*)d_in[2];
  const int*   v_mask   = (const int*)d_in[3];
  const float* t_action = (const float*)d_in[4];
  const float* t_frame  = (const float*)d_in[5];
  const float* t_task   = (const float*)d_in[6];
  const int*   t_mask   = (const int*)d_in[7];
  const float* v_aw = (const float*)d_in[16];
  const float* t_aw = (const float*)d_in[17];
  const float* v_tw = (const float*)d_in[18];
  const float* v_tb = (const float*)d_in[19];
  const float* t_tw = (const float*)d_in[20];
  const float* t_tb = (const float*)d_in[21];

  const long long TBH = (long long)T_DIM * B_DIM * H_DIM;
  const long long BTN = (long long)B_DIM * T_DIM * N_DIM;
  const long long NBH = (long long)N_DIM * B_DIM * H_DIM;
  const long long WS  = (long long)H_DIM * H_DIM;

  float* out = (float*)d_out;
  float* out_v   = out;
  float* out_t   = out + TBH;
  float* out_vnm = out + 2 * TBH;
  float* out_tnm = out + 2 * TBH + BTN;
  float* out_vta = out + 2 * TBH + 2 * BTN;
  float* out_tta = out_vta + NT_DIM * B_DIM;

  char* w = (char*)d_ws;
  auto alloc = [&](long long bytes) {
    char* p = w; w += (bytes + 255) & ~255LL; return p;
  };
  short* WT  = (short*)alloc(8 * WS * 2);
  short* Qv  = (short*)alloc(TBH * 2);      // reused as midv
  short* Qt  = (short*)alloc(TBH * 2);      // reused as midt
  short* KVv = (short*)alloc(2048LL * 1024 * 2);
  short* KVt = (short*)alloc(2048LL * 1024 * 2);
  short* VTv = (short*)alloc(NBH * 2);
  short* VTt = (short*)alloc(NBH * 2);
  short* Av  = (short*)alloc(BTN * 2);
  short* At  = (short*)alloc(BTN * 2);
  short* Lv  = (short*)alloc(BTN * 2);
  short* Lt  = (short*)alloc(BTN * 2);
  short* midv = Qv;
  short* midt = Qt;

  const float rsq = 0.044194173824159216f;  // 1/sqrt(512)

  // 1. weight transpose + cvt
  WSrc ws8;
  for (int i = 0; i < 8; ++i) ws8.p[i] = (const float*)d_in[8 + i];
  wtrans_kernel<<<dim3(16, 16, 8), dim3(32, 8), 0, stream>>>(ws8, WT);

  // 2. Q projections (f32 A)
  gemm_tn<float, short, false><<<dim3(256, 4, 1), dim3(256), 0, stream>>>(
      v_frame, 0LL, H_DIM, WT + 0 * WS, 0LL, H_DIM, Qv, 0LL, H_DIM, nullptr, 512, 1.f);
  gemm_tn<float, short, false><<<dim3(256, 4, 1), dim3(256), 0, stream>>>(
      t_frame, 0LL, H_DIM, WT + 4 * WS, 0LL, H_DIM, Qt, 0LL, H_DIM, nullptr, 512, 1.f);

  // 3. merged K|V projections (Wk^T,Wv^T adjacent in WT)
  gemm_tn<float, short, false><<<dim3(16, 8, 1), dim3(256), 0, stream>>>(
      v_action, 0LL, H_DIM, WT + 1 * WS, 0LL, H_DIM, KVv, 0LL, 1024, nullptr, 512, 1.f);
  gemm_tn<float, short, false><<<dim3(16, 8, 1), dim3(256), 0, stream>>>(
      t_action, 0LL, H_DIM, WT + 5 * WS, 0LL, H_DIM, KVt, 0LL, 1024, nullptr, 512, 1.f);

  // 4. V transpose -> VT[b][h][n]
  vtrans_kernel<<<dim3(16, 8, 16), dim3(32, 8), 0, stream>>>(KVv, KVt, VTv, VTt);

  // 5. logits (bf16 out) [B,T,N]
  gemm_tn<short, short, false><<<dim3(32, 2, 8), dim3(256), 0, stream>>>(
      Qv, 512LL, B_DIM * H_DIM, KVv, 1024LL, 8192, Lv,
      (long long)T_DIM * N_DIM, N_DIM, nullptr, 512, rsq);
  gemm_tn<short, short, false><<<dim3(32, 2, 8), dim3(256), 0, stream>>>(
      Qt, 512LL, B_DIM * H_DIM, KVt, 1024LL, 8192, Lt,
      (long long)T_DIM * N_DIM, N_DIM, nullptr, 512, rsq);

  // 6. fused combine + softmax + nomask-transpose (writes out_nm directly)
  softmax_fused<<<dim3(T_DIM / 16, B_DIM), dim3(256), 0, stream>>>(
      Lv, Lt, v_mask, t_mask, v_aw, t_aw, Av, At, out_vnm, out_tnm);

  // 7. attn @ V
  gemm_tn<short, short, false><<<dim3(32, 4, 8), dim3(256), 0, stream>>>(
      Av, (long long)T_DIM * N_DIM, N_DIM, VTv, (long long)H_DIM * N_DIM, N_DIM,
      midv, 512LL, B_DIM * H_DIM, nullptr, 256, 1.f);
  gemm_tn<short, short, false><<<dim3(32, 4, 8), dim3(256), 0, stream>>>(
      At, (long long)T_DIM * N_DIM, N_DIM, VTt, (long long)H_DIM * N_DIM, N_DIM,
      midt, 512LL, B_DIM * H_DIM, nullptr, 256, 1.f);

  // 8. output projection + residual
  gemm_tn<short, float, true><<<dim3(256, 4, 1), dim3(256), 0, stream>>>(
      midv, 0LL, H_DIM, WT + 3 * WS, 0LL, H_DIM, out_v, 0LL, H_DIM, v_frame, 512, 1.f);
  gemm_tn<short, float, true><<<dim3(256, 4, 1), dim3(256), 0, stream>>>(
      midt, 0LL, H_DIM, WT + 7 * WS, 0LL, H_DIM, out_t, 0LL, H_DIM, t_frame, 512, 1.f);

  // 9. task heads
  task_kernel<<<dim3(1), dim3(1024), 0, stream>>>(
      v_task, t_task, v_tw, v_tb, t_tw, t_tb, out_vta, out_tta);
}

// Round 3
// 439.378 us; speedup vs baseline: 1.0942x; 1.0057x over previous
//
#include <hip/hip_runtime.h>
#include <hip/hip_bf16.h>
#include <cstddef>
#include <cstdint>

#define T_DIM 4096
#define B_DIM 8
#define N_DIM 256
#define H_DIM 512
#define NT_DIM 5

typedef __attribute__((ext_vector_type(8))) short short8;
typedef __attribute__((ext_vector_type(4))) short short4v;
typedef __attribute__((ext_vector_type(4))) float f32x4;

__device__ __forceinline__ short cvt_bf16(float f) {
  __hip_bfloat16 h = __float2bfloat16(f);   // compiler emits HW cvt (m240)
  union { __hip_bfloat16 h; short s; } u; u.h = h; return u.s;
}
__device__ __forceinline__ float bf2f(short s) {
  union { uint32_t u; float f; } v; v.u = ((uint32_t)(uint16_t)s) << 16;
  return v.f;
}

// async global->LDS, 16B per lane; LDS dest = wave-uniform base + lane*16
typedef __attribute__((address_space(1))) const void gvoid_t;
typedef __attribute__((address_space(3))) void lvoid_t;
__device__ __forceinline__ void gl_lds16(const void* g, void* lds_wave_base) {
  __builtin_amdgcn_global_load_lds((gvoid_t*)(uintptr_t)g,
                                   (lvoid_t*)(uint32_t)(uintptr_t)lds_wave_base,
                                   16, 0, 0);
}

// dual-domain pointer set: dom = blockIdx.z >> zlog, zz = blockIdx.z & mask
struct GP {
  const void* A[2];
  const short* B[2];
  void* C[2];
  const float* R[2];
};

// ---------------------------------------------------------------------------
// TN GEMM: C[m,n] = scale * sum_k A[m,k] * Bt[n,k]  (+ Res[m,n])
// 128x128 tile, 4 waves, BK=32, 16x16x32 bf16 MFMA.
// B staged via global_load_lds (linear LDS [128][32]).
// A: bf16 -> global_load_lds; f32 -> reg-staged cvt into padded LDS [128][40].
// ---------------------------------------------------------------------------
template<typename TA, typename TC, bool ADD_RES>
__global__ __launch_bounds__(256)
void gemm_tn(GP p, int zlog, long long a_bs, int lda,
             long long b_bs, int ldb, long long c_bs, int ldc,
             int K, float scale) {
  constexpr int AS_STRIDE = (sizeof(TA) == 4) ? 40 : 32;
  __shared__ short As[128 * AS_STRIDE];
  __shared__ short Bs[128 * 32];

  const int tid  = threadIdx.x;
  const int lane = tid & 63;
  const int wave = tid >> 6;
  const int wr   = (wave >> 1) * 64;
  const int wc   = (wave & 1) * 64;
  const int lrow = lane & 15;
  const int kgrp = lane >> 4;

  const int dom = blockIdx.z >> zlog;
  const long long zz = blockIdx.z & ((1u << zlog) - 1u);

  const TA*    Ab = (const TA*)p.A[dom] + zz * a_bs + (long long)(blockIdx.x * 128) * lda;
  const short* Bb = p.B[dom] + zz * b_bs + (long long)(blockIdx.y * 128) * ldb;

  // lds-direct chunk geometry: chunk c covers rows c*16..c*16+15 (1 KiB)
  const int ch_r = lane >> 2;
  const int ch_c = (lane & 3) * 8;
  // f32 reg-stage geometry
  const int srow = tid >> 1;
  const int scol = (tid & 1) * 16;

  f32x4 acc[4][4] = {};

  for (int k0 = 0; k0 < K; k0 += 32) {
    __syncthreads();
    if constexpr (sizeof(TA) == 4) {
      const TA* gp = Ab + (long long)srow * lda + k0 + scol;
      f32x4 v0 = *(const f32x4*)(gp + 0);
      f32x4 v1 = *(const f32x4*)(gp + 4);
      f32x4 v2 = *(const f32x4*)(gp + 8);
      f32x4 v3 = *(const f32x4*)(gp + 12);
      short8 s0, s1;
      #pragma unroll
      for (int e = 0; e < 4; ++e) {
        s0[e]     = cvt_bf16(v0[e]);
        s0[4 + e] = cvt_bf16(v1[e]);
        s1[e]     = cvt_bf16(v2[e]);
        s1[4 + e] = cvt_bf16(v3[e]);
      }
      *(short8*)&As[srow * AS_STRIDE + scol]     = s0;
      *(short8*)&As[srow * AS_STRIDE + scol + 8] = s1;
    } else {
      #pragma unroll
      for (int i = 0; i < 2; ++i) {
        const int c = wave + 4 * i;
        gl_lds16((const short*)Ab + (long long)(c * 16 + ch_r) * lda + k0 + ch_c,
                 &As[c * 512]);
      }
    }
    #pragma unroll
    for (int i = 0; i < 2; ++i) {
      const int c = wave + 4 * i;
      gl_lds16(Bb + (long long)(c * 16 + ch_r) * ldb + k0 + ch_c, &Bs[c * 512]);
    }
    __syncthreads();

    short8 af[4], bfr[4];
    #pragma unroll
    for (int i = 0; i < 4; ++i)
      af[i] = *(const short8*)&As[(wr + i * 16 + lrow) * AS_STRIDE + kgrp * 8];
    #pragma unroll
    for (int j = 0; j < 4; ++j)
      bfr[j] = *(const short8*)&Bs[(wc + j * 16 + lrow) * 32 + kgrp * 8];
    #pragma unroll
    for (int i = 0; i < 4; ++i)
      #pragma unroll
      for (int j = 0; j < 4; ++j)
        acc[i][j] = __builtin_amdgcn_mfma_f32_16x16x32_bf16(af[i], bfr[j], acc[i][j], 0, 0, 0);
  }

  TC* Cd = (TC*)p.C[dom];
  const float* Res = p.R[dom];
  const long long cb = zz * c_bs;
  const int gm = blockIdx.x * 128 + wr;
  const int gn = blockIdx.y * 128 + wc;
  #pragma unroll
  for (int i = 0; i < 4; ++i) {
    #pragma unroll
    for (int j = 0; j < 4; ++j) {
      const int col = gn + j * 16 + lrow;
      #pragma unroll
      for (int r = 0; r < 4; ++r) {
        const int row = gm + i * 16 + kgrp * 4 + r;
        const long long idx = cb + (long long)row * ldc + col;
        float v = acc[i][j][r] * scale;
        if constexpr (ADD_RES) v += Res[idx];
        if constexpr (sizeof(TC) == 2) Cd[idx] = cvt_bf16(v);
        else                           Cd[idx] = v;
      }
    }
  }
}

// ---------------------------------------------------------------------------
// Weight transpose + cvt: WT[w][n][k] = bf16(W[w][k][n]), 8 matrices 512x512
// ---------------------------------------------------------------------------
struct WSrc { const float* p[8]; };

__global__ __launch_bounds__(256)
void wtrans_kernel(WSrc s, short* __restrict__ dst) {
  __shared__ float tile[32][33];
  const int w = blockIdx.z;
  const float* src = s.p[w];
  short* d = dst + (long long)w * H_DIM * H_DIM;
  const int tx = threadIdx.x, ty = threadIdx.y;
  const int n0 = blockIdx.x * 32, k0 = blockIdx.y * 32;
  #pragma unroll
  for (int i = 0; i < 4; ++i)
    tile[ty + 8 * i][tx] = src[(long long)(k0 + ty + 8 * i) * H_DIM + n0 + tx];
  __syncthreads();
  #pragma unroll
  for (int i = 0; i < 4; ++i)
    d[(long long)(n0 + ty + 8 * i) * H_DIM + k0 + tx] = cvt_bf16(tile[tx][ty + 8 * i]);
}

// ---------------------------------------------------------------------------
// V transpose from merged KV: VT[b][h][n] = KV[(n*8+b)*1024 + 512 + h]
// ---------------------------------------------------------------------------
__global__ __launch_bounds__(256)
void vtrans_kernel(const short* __restrict__ KVv, const short* __restrict__ KVt,
                   short* __restrict__ VTv, short* __restrict__ VTt) {
  __shared__ short tile[32][33];
  const int z = blockIdx.z;
  const int dom = z >> 3, b = z & 7;
  const short* src = (dom ? KVt : KVv) + b * 1024 + 512;
  short* dst = (dom ? VTt : VTv) + (long long)b * H_DIM * N_DIM;
  const int tx = threadIdx.x, ty = threadIdx.y;
  const int h0 = blockIdx.x * 32, n0 = blockIdx.y * 32;
  #pragma unroll
  for (int i = 0; i < 4; ++i)
    tile[ty + 8 * i][tx] = src[(long long)(n0 + ty + 8 * i) * 8192 + h0 + tx];
  __syncthreads();
  #pragma unroll
  for (int i = 0; i < 4; ++i)
    dst[(long long)(h0 + ty + 8 * i) * N_DIM + n0 + tx] = tile[tx][ty + 8 * i];
}

// ---------------------------------------------------------------------------
// Fused: combine + masked softmax + bf16 attn + nomask transpose to d_out.
// Grid (T/16, B), 256 thr. r=tid>>4 (t-row), seg=tid&15 (16-col slice).
// ---------------------------------------------------------------------------
__global__ __launch_bounds__(256)
void softmax_fused(const short* __restrict__ Lv, const short* __restrict__ Lt,
                   const int* __restrict__ vmask, const int* __restrict__ tmask,
                   const float* __restrict__ vaw, const float* __restrict__ taw,
                   short* __restrict__ Av, short* __restrict__ At,
                   float* __restrict__ Onm_v, float* __restrict__ Onm_t) {
  __shared__ float tile[16 * 260];
  __shared__ int msk[2][256];
  const int tid = threadIdx.x;
  const int b = blockIdx.y, t0 = blockIdx.x * 16;
  const int r = tid >> 4, seg = tid & 15;
  msk[0][tid] = vmask[b * 256 + tid];
  msk[1][tid] = tmask[b * 256 + tid];
  __syncthreads();
  const float sv = 1.f / (1.f + __expf(-vaw[0]));
  const float st = 1.f / (1.f + __expf(-taw[0]));
  const long long off = ((long long)b * T_DIM + t0 + r) * N_DIM + seg * 16;

  short8 lv0 = *(const short8*)&Lv[off];
  short8 lv1 = *(const short8*)&Lv[off + 8];
  short8 lt0 = *(const short8*)&Lt[off];
  short8 lt1 = *(const short8*)&Lt[off + 8];
  float cv[16], ct[16];
  #pragma unroll
  for (int i = 0; i < 8; ++i) {
    float a0 = bf2f(lv0[i]), b0 = bf2f(lt0[i]);
    float a1 = bf2f(lv1[i]), b1 = bf2f(lt1[i]);
    cv[i]     = a0 + sv * b0;  ct[i]     = b0 + st * a0;
    cv[8 + i] = a1 + sv * b1;  ct[8 + i] = b1 + st * a1;
  }

#define EMIT_DOMAIN(CVAL, DI, AOUT, ONM) do {                                   \
    const int4 mA = *(const int4*)&msk[DI][seg * 16 + 0];                       \
    const int4 mB = *(const int4*)&msk[DI][seg * 16 + 4];                       \
    const int4 mC = *(const int4*)&msk[DI][seg * 16 + 8];                       \
    const int4 mD = *(const int4*)&msk[DI][seg * 16 + 12];                      \
    const int mk[16] = {mA.x, mA.y, mA.z, mA.w, mB.x, mB.y, mB.z, mB.w,         \
                        mC.x, mC.y, mC.z, mC.w, mD.x, mD.y, mD.z, mD.w};        \
    float mx = -3.4e38f;                                                        \
    _Pragma("unroll")                                                           \
    for (int q = 0; q < 16; ++q) if (mk[q] > 0) mx = fmaxf(mx, CVAL[q]);        \
    _Pragma("unroll")                                                           \
    for (int sh = 1; sh < 16; sh <<= 1) mx = fmaxf(mx, __shfl_xor(mx, sh));     \
    float ev[16]; float ssum = 0.f;                                             \
    _Pragma("unroll")                                                           \
    for (int q = 0; q < 16; ++q) {                                              \
      ev[q] = (mk[q] > 0) ? __expf(CVAL[q] - mx) : 0.f; ssum += ev[q];          \
    }                                                                           \
    _Pragma("unroll")                                                           \
    for (int sh = 1; sh < 16; sh <<= 1) ssum += __shfl_xor(ssum, sh);           \
    const float inv = 1.f / ssum;                                               \
    short8 o0, o1;                                                              \
    _Pragma("unroll")                                                           \
    for (int q = 0; q < 8; ++q) {                                               \
      o0[q] = cvt_bf16(ev[q] * inv); o1[q] = cvt_bf16(ev[8 + q] * inv);         \
    }                                                                           \
    *(short8*)&AOUT[off] = o0; *(short8*)&AOUT[off + 8] = o1;                   \
    _Pragma("unroll")                                                           \
    for (int q = 0; q < 4; ++q) {                                               \
      f32x4 tv; tv[0] = CVAL[q * 4]; tv[1] = CVAL[q * 4 + 1];                   \
      tv[2] = CVAL[q * 4 + 2]; tv[3] = CVAL[q * 4 + 3];                         \
      *(f32x4*)&tile[r * 260 + seg * 16 + q * 4] = tv;                          \
    }                                                                           \
    __syncthreads();                                                            \
    {                                                                           \
      float* obase = &ONM[((long long)b * N_DIM + tid) * T_DIM + t0];           \
      _Pragma("unroll")                                                         \
      for (int g = 0; g < 4; ++g) {                                             \
        f32x4 wv;                                                               \
        wv[0] = tile[(4 * g + 0) * 260 + tid];                                  \
        wv[1] = tile[(4 * g + 1) * 260 + tid];                                  \
        wv[2] = tile[(4 * g + 2) * 260 + tid];                                  \
        wv[3] = tile[(4 * g + 3) * 260 + tid];                                  \
        *(f32x4*)&obase[4 * g] = wv;                                            \
      }                                                                         \
    }                                                                           \
    __syncthreads();                                                            \
  } while (0)

  EMIT_DOMAIN(cv, 0, Av, Onm_v);
  EMIT_DOMAIN(ct, 1, At, Onm_t);
#undef EMIT_DOMAIN
}

// ---------------------------------------------------------------------------
// Task heads
// ---------------------------------------------------------------------------
__global__ __launch_bounds__(1024)
void task_kernel(const float* __restrict__ vtask, const float* __restrict__ ttask,
                 const float* __restrict__ vtw, const float* __restrict__ vtb,
                 const float* __restrict__ ttw, const float* __restrict__ ttb,
                 float* __restrict__ out_v, float* __restrict__ out_t) {
  const int wave = threadIdx.x >> 6;
  const int lane = threadIdx.x & 63;
  const int dom = wave >> 3;
  const int b   = wave & 7;
  const float* task = dom ? ttask : vtask;
  const float* tw   = dom ? ttw : vtw;
  const float  tb   = (dom ? ttb : vtb)[0];
  float* o = dom ? out_t : out_v;
  for (int k = 0; k < NT_DIM; ++k) {
    const float* row = task + ((long long)k * B_DIM + b) * H_DIM;
    float s = 0.f;
    for (int c = lane; c < H_DIM; c += 64) s += row[c] * tw[c];
    #pragma unroll
    for (int d = 32; d > 0; d >>= 1) s += __shfl_xor(s, d);
    if (lane == 0) o[k * B_DIM + b] = s + tb;
  }
}

// ---------------------------------------------------------------------------
extern "C" void kernel_launch(void* const* d_in, const int* in_sizes, int n_in,
                              void* d_out, int out_size, void* d_ws, size_t ws_size,
                              hipStream_t stream) {
  const float* v_action = (const float*)d_in[0];
  const float* v_frame  = (const float*)d_in[1];
  const float* v_task   = (const float*)d_in[2];
  const int*   v_mask   = (const int*)d_in[3];
  const float* t_action = (const float*)d_in[4];
  const float* t_frame  = (const float*)d_in[5];
  const float* t_task   = (const float*)d_in[6];
  const int*   t_mask   = (const int*)d_in[7];
  const float* v_aw = (const float*)d_in[16];
  const float* t_aw = (const float*)d_in[17];
  const float* v_tw = (const float*)d_in[18];
  const float* v_tb = (const float*)d_in[19];
  const float* t_tw = (const float*)d_in[20];
  const float* t_tb = (const float*)d_in[21];

  const long long TBH = (long long)T_DIM * B_DIM * H_DIM;
  const long long BTN = (long long)B_DIM * T_DIM * N_DIM;
  const long long NBH = (long long)N_DIM * B_DIM * H_DIM;
  const long long WS  = (long long)H_DIM * H_DIM;

  float* out = (float*)d_out;
  float* out_v   = out;
  float* out_t   = out + TBH;
  float* out_vnm = out + 2 * TBH;
  float* out_tnm = out + 2 * TBH + BTN;
  float* out_vta = out + 2 * TBH + 2 * BTN;
  float* out_tta = out_vta + NT_DIM * B_DIM;

  char* w = (char*)d_ws;
  auto alloc = [&](long long bytes) {
    char* p = w; w += (bytes + 255) & ~255LL; return p;
  };
  short* WT  = (short*)alloc(8 * WS * 2);
  short* Qv  = (short*)alloc(TBH * 2);      // reused as midv
  short* Qt  = (short*)alloc(TBH * 2);      // reused as midt
  short* KVv = (short*)alloc(2048LL * 1024 * 2);
  short* KVt = (short*)alloc(2048LL * 1024 * 2);
  short* VTv = (short*)alloc(NBH * 2);
  short* VTt = (short*)alloc(NBH * 2);
  short* Av  = (short*)alloc(BTN * 2);
  short* At  = (short*)alloc(BTN * 2);
  short* Lv  = (short*)alloc(BTN * 2);
  short* Lt  = (short*)alloc(BTN * 2);
  short* midv = Qv;
  short* midt = Qt;

  const float rsq = 0.044194173824159216f;  // 1/sqrt(512)

  // 1. weight transpose + cvt
  WSrc ws8;
  for (int i = 0; i < 8; ++i) ws8.p[i] = (const float*)d_in[8 + i];
  wtrans_kernel<<<dim3(16, 16, 8), dim3(32, 8), 0, stream>>>(ws8, WT);

  // 2. Q projections (f32 A), both domains in one launch
  {
    GP p = {{v_frame, t_frame}, {WT + 0 * WS, WT + 4 * WS}, {Qv, Qt}, {nullptr, nullptr}};
    gemm_tn<float, short, false><<<dim3(256, 4, 2), dim3(256), 0, stream>>>(
        p, 0, 0LL, H_DIM, 0LL, H_DIM, 0LL, H_DIM, 512, 1.f);
  }

  // 3. merged K|V projections (Wk^T,Wv^T adjacent in WT), both domains
  {
    GP p = {{v_action, t_action}, {WT + 1 * WS, WT + 5 * WS}, {KVv, KVt}, {nullptr, nullptr}};
    gemm_tn<float, short, false><<<dim3(16, 8, 2), dim3(256), 0, stream>>>(
        p, 0, 0LL, H_DIM, 0LL, H_DIM, 0LL, 1024, 512, 1.f);
  }

  // 4. V transpose -> VT[b][h][n]
  vtrans_kernel<<<dim3(16, 8, 16), dim3(32, 8), 0, stream>>>(KVv, KVt, VTv, VTt);

  // 5. logits (bf16 out) [B,T,N], both domains (z = dom*8 + b)
  {
    GP p = {{Qv, Qt}, {KVv, KVt}, {Lv, Lt}, {nullptr, nullptr}};
    gemm_tn<short, short, false><<<dim3(32, 2, 16), dim3(256), 0, stream>>>(
        p, 3, 512LL, B_DIM * H_DIM, 1024LL, 8192,
        (long long)T_DIM * N_DIM, N_DIM, 512, rsq);
  }

  // 6. fused combine + softmax + nomask-transpose (writes out_nm directly)
  softmax_fused<<<dim3(T_DIM / 16, B_DIM), dim3(256), 0, stream>>>(
      Lv, Lt, v_mask, t_mask, v_aw, t_aw, Av, At, out_vnm, out_tnm);

  // 7. attn @ V, both domains
  {
    GP p = {{Av, At}, {VTv, VTt}, {midv, midt}, {nullptr, nullptr}};
    gemm_tn<short, short, false><<<dim3(32, 4, 16), dim3(256), 0, stream>>>(
        p, 3, (long long)T_DIM * N_DIM, N_DIM, (long long)H_DIM * N_DIM, N_DIM,
        512LL, B_DIM * H_DIM, 256, 1.f);
  }

  // 8. output projection + residual, both domains
  {
    GP p = {{midv, midt}, {WT + 3 * WS, WT + 7 * WS}, {out_v, out_t}, {v_frame, t_frame}};
    gemm_tn<short, float, true><<<dim3(256, 4, 2), dim3(256), 0, stream>>>(
        p, 0, 0LL, H_DIM, 0LL, H_DIM, 0LL, H_DIM, 512, 1.f);
  }

  // 9. task heads
  task_kernel<<<dim3(1), dim3(1024), 0, stream>>>(
      v_task, t_task, v_tw, v_tb, t_tw, t_tb, out_vta, out_tta);
}

// Round 4
// 363.865 us; speedup vs baseline: 1.3213x; 1.2075x over previous
//
#include <hip/hip_runtime.h>
#include <hip/hip_bf16.h>
#include <cstddef>
#include <cstdint>

#define T_DIM 4096
#define B_DIM 8
#define N_DIM 256
#define H_DIM 512
#define NT_DIM 5

typedef __attribute__((ext_vector_type(8))) short short8;
typedef __attribute__((ext_vector_type(4))) float f32x4;

__device__ __forceinline__ short cvt_bf16(float f) {
  __hip_bfloat16 h = __float2bfloat16(f);   // HW cvt path (m240)
  union { __hip_bfloat16 h; short s; } u; u.h = h; return u.s;
}
__device__ __forceinline__ float bf2f(short s) {
  union { uint32_t u; float f; } v; v.u = ((uint32_t)(uint16_t)s) << 16;
  return v.f;
}

// async global->LDS, 16B/lane; LDS dest = wave-uniform base + lane*16
typedef __attribute__((address_space(1))) const void gvoid_t;
typedef __attribute__((address_space(3))) void lvoid_t;
__device__ __forceinline__ void gl_lds16(const void* g, void* lds_wave_base) {
  __builtin_amdgcn_global_load_lds((gvoid_t*)(uintptr_t)g,
                                   (lvoid_t*)(uint32_t)(uintptr_t)lds_wave_base,
                                   16, 0, 0);
}

// dual-domain pointer set: dom = blockIdx.z >> zlog, zz = blockIdx.z & mask
struct GP {
  const void* A[2];
  const short* B[2];
  void* C[2];
  const float* R[2];
};

// ---------------------------------------------------------------------------
// TN GEMM: C[m,n] = scale * sum_k A[m,k] * Bt[n,k]  (+ Res[m,n])
// 128x128 tile, 4 waves, 16x16x32 bf16 MFMA.
// bf16 A/B staged via global_load_lds, BK=64, XOR-swizzled (both-sides, rule21).
// f32 A: reg-staged cvt into padded LDS [128][40], BK=32.
// Epilogue: per-wave LDS restage (stride 68 -> 2-way max) -> coalesced
// dwordx4 stores + coalesced Res loads.
// ---------------------------------------------------------------------------
template<typename TA, typename TC, bool ADD_RES>
__global__ __launch_bounds__(256)
void gemm_tn(GP p, int zlog, long long a_bs, int lda,
             long long b_bs, int ldb, long long c_bs, int ldc,
             int K, float scale) {
  constexpr bool F32A = (sizeof(TA) == 4);
  constexpr int BK = F32A ? 32 : 64;
  constexpr int ASTR = F32A ? 40 : 64;
  constexpr int ABYTES = 128 * ASTR * 2;
  constexpr int BBYTES = 128 * BK * 2;
  constexpr int EPIB = 4 * 16 * 68 * 4;
  constexpr int SMEMB = (ABYTES + BBYTES) > EPIB ? (ABYTES + BBYTES) : EPIB;
  __shared__ __align__(16) char smem[SMEMB];
  short* As = (short*)smem;
  short* Bs = (short*)(smem + ABYTES);

  const int tid  = threadIdx.x;
  const int lane = tid & 63;
  const int wave = tid >> 6;
  const int wr   = (wave >> 1) * 64;
  const int wc   = (wave & 1) * 64;
  const int lrow = lane & 15;
  const int kgrp = lane >> 4;

  const int dom = blockIdx.z >> zlog;
  const long long zz = blockIdx.z & ((1u << zlog) - 1u);

  const TA*    Ab = (const TA*)p.A[dom] + zz * a_bs + (long long)(blockIdx.x * 128) * lda;
  const short* Bb = p.B[dom] + zz * b_bs + (long long)(blockIdx.y * 128) * ldb;

  // f32 reg-stage geometry
  const int srow = tid >> 1;
  const int scol = (tid & 1) * 16;

  f32x4 acc[4][4] = {};

  for (int k0 = 0; k0 < K; k0 += BK) {
    __syncthreads();
    if constexpr (F32A) {
      const float* gp = (const float*)Ab + (long long)srow * lda + k0 + scol;
      f32x4 v0 = *(const f32x4*)(gp + 0);
      f32x4 v1 = *(const f32x4*)(gp + 4);
      f32x4 v2 = *(const f32x4*)(gp + 8);
      f32x4 v3 = *(const f32x4*)(gp + 12);
      short8 s0, s1;
      #pragma unroll
      for (int e = 0; e < 4; ++e) {
        s0[e]     = cvt_bf16(v0[e]);
        s0[4 + e] = cvt_bf16(v1[e]);
        s1[e]     = cvt_bf16(v2[e]);
        s1[4 + e] = cvt_bf16(v3[e]);
      }
      *(short8*)&As[srow * ASTR + scol]     = s0;
      *(short8*)&As[srow * ASTR + scol + 8] = s1;
    } else {
      #pragma unroll
      for (int i = 0; i < 4; ++i) {
        const int c = wave + 4 * i;           // chunk: 8 rows x 64 shorts
        const int row = c * 8 + (lane >> 3);
        const int col = ((lane & 7) ^ (row & 7)) * 8;   // pre-swizzled source
        gl_lds16((const short*)Ab + (long long)row * lda + k0 + col, &As[c * 512]);
      }
    }
    if constexpr (BK == 64) {
      #pragma unroll
      for (int i = 0; i < 4; ++i) {
        const int c = wave + 4 * i;
        const int row = c * 8 + (lane >> 3);
        const int col = ((lane & 7) ^ (row & 7)) * 8;
        gl_lds16(Bb + (long long)row * ldb + k0 + col, &Bs[c * 512]);
      }
    } else {
      #pragma unroll
      for (int i = 0; i < 2; ++i) {
        const int c = wave + 4 * i;           // chunk: 16 rows x 32 shorts
        const int row = c * 16 + (lane >> 2);
        const int col = ((lane & 3) ^ (row & 3)) * 8;
        gl_lds16(Bb + (long long)row * ldb + k0 + col, &Bs[c * 512]);
      }
    }
    __syncthreads();

    #pragma unroll
    for (int kk = 0; kk < BK / 32; ++kk) {
      short8 af[4], bfr[4];
      #pragma unroll
      for (int i = 0; i < 4; ++i) {
        const int row = wr + i * 16 + lrow;
        if constexpr (F32A) {
          af[i] = *(const short8*)&As[row * ASTR + kgrp * 8 + kk * 32];
        } else {
          const int u = (kgrp + 4 * kk) ^ (row & 7);    // swizzled read
          af[i] = *(const short8*)&As[row * 64 + u * 8];
        }
      }
      #pragma unroll
      for (int j = 0; j < 4; ++j) {
        const int row = wc + j * 16 + lrow;
        if constexpr (BK == 64) {
          const int u = (kgrp + 4 * kk) ^ (row & 7);
          bfr[j] = *(const short8*)&Bs[row * 64 + u * 8];
        } else {
          const int u = kgrp ^ (row & 3);
          bfr[j] = *(const short8*)&Bs[row * 32 + u * 8];
        }
      }
      #pragma unroll
      for (int i = 0; i < 4; ++i)
        #pragma unroll
        for (int j = 0; j < 4; ++j)
          acc[i][j] = __builtin_amdgcn_mfma_f32_16x16x32_bf16(af[i], bfr[j], acc[i][j], 0, 0, 0);
    }
  }

  // ---- epilogue: LDS restage -> coalesced vector stores ----
  __syncthreads();   // all waves done reading As/Bs
  float* myEp = (float*)smem + wave * (16 * 68);
  TC* Cd = (TC*)p.C[dom];
  const float* Res = p.R[dom];
  const long long cb = zz * c_bs;
  const int gm = blockIdx.x * 128 + wr;
  const int gn = blockIdx.y * 128 + wc;
  const int er = lane >> 2;          // read-back row 0..15
  const int ec = (lane & 3) * 16;    // read-back col base

  #pragma unroll
  for (int i = 0; i < 4; ++i) {
    #pragma unroll
    for (int j = 0; j < 4; ++j)
      #pragma unroll
      for (int r = 0; r < 4; ++r)
        myEp[(kgrp * 4 + r) * 68 + j * 16 + lrow] = acc[i][j][r];
    // wave-local write->read; compiler orders via lgkmcnt
    float vals[16];
    #pragma unroll
    for (int q = 0; q < 4; ++q) {
      f32x4 t4 = *(const f32x4*)&myEp[er * 68 + ec + q * 4];
      vals[q * 4 + 0] = t4[0]; vals[q * 4 + 1] = t4[1];
      vals[q * 4 + 2] = t4[2]; vals[q * 4 + 3] = t4[3];
    }
    const int row_g = gm + i * 16 + er;
    const long long base = cb + (long long)row_g * ldc + gn + ec;
    if constexpr (sizeof(TC) == 2) {
      short8 s0, s1;
      #pragma unroll
      for (int e = 0; e < 8; ++e) {
        s0[e] = cvt_bf16(vals[e] * scale);
        s1[e] = cvt_bf16(vals[8 + e] * scale);
      }
      *(short8*)&Cd[base]     = s0;
      *(short8*)&Cd[base + 8] = s1;
    } else {
      #pragma unroll
      for (int q = 0; q < 4; ++q) {
        f32x4 o;
        #pragma unroll
        for (int e = 0; e < 4; ++e) o[e] = vals[q * 4 + e] * scale;
        if constexpr (ADD_RES) {
          f32x4 rr = *(const f32x4*)&Res[base + q * 4];
          #pragma unroll
          for (int e = 0; e < 4; ++e) o[e] += rr[e];
        }
        *(f32x4*)&Cd[base + q * 4] = o;
      }
    }
  }
}

// ---------------------------------------------------------------------------
// Weight transpose + cvt: WT[w][n][k] = bf16(W[w][k][n]), 8 matrices 512x512
// ---------------------------------------------------------------------------
struct WSrc { const float* p[8]; };

__global__ __launch_bounds__(256)
void wtrans_kernel(WSrc s, short* __restrict__ dst) {
  __shared__ float tile[32][33];
  const int w = blockIdx.z;
  const float* src = s.p[w];
  short* d = dst + (long long)w * H_DIM * H_DIM;
  const int tx = threadIdx.x, ty = threadIdx.y;
  const int n0 = blockIdx.x * 32, k0 = blockIdx.y * 32;
  #pragma unroll
  for (int i = 0; i < 4; ++i)
    tile[ty + 8 * i][tx] = src[(long long)(k0 + ty + 8 * i) * H_DIM + n0 + tx];
  __syncthreads();
  #pragma unroll
  for (int i = 0; i < 4; ++i)
    d[(long long)(n0 + ty + 8 * i) * H_DIM + k0 + tx] = cvt_bf16(tile[tx][ty + 8 * i]);
}

// ---------------------------------------------------------------------------
// V transpose from merged KV: VT[b][h][n] = KV[(n*8+b)*1024 + 512 + h]
// ---------------------------------------------------------------------------
__global__ __launch_bounds__(256)
void vtrans_kernel(const short* __restrict__ KVv, const short* __restrict__ KVt,
                   short* __restrict__ VTv, short* __restrict__ VTt) {
  __shared__ short tile[32][33];
  const int z = blockIdx.z;
  const int dom = z >> 3, b = z & 7;
  const short* src = (dom ? KVt : KVv) + b * 1024 + 512;
  short* dst = (dom ? VTt : VTv) + (long long)b * H_DIM * N_DIM;
  const int tx = threadIdx.x, ty = threadIdx.y;
  const int h0 = blockIdx.x * 32, n0 = blockIdx.y * 32;
  #pragma unroll
  for (int i = 0; i < 4; ++i)
    tile[ty + 8 * i][tx] = src[(long long)(n0 + ty + 8 * i) * 8192 + h0 + tx];
  __syncthreads();
  #pragma unroll
  for (int i = 0; i < 4; ++i)
    dst[(long long)(h0 + ty + 8 * i) * N_DIM + n0 + tx] = tile[tx][ty + 8 * i];
}

// ---------------------------------------------------------------------------
// Fused: combine + masked softmax + bf16 attn + nomask transpose to d_out.
// Grid (T/16, B), 256 thr. r=tid>>4 (t-row), seg=tid&15 (16-col slice).
// ---------------------------------------------------------------------------
__global__ __launch_bounds__(256)
void softmax_fused(const short* __restrict__ Lv, const short* __restrict__ Lt,
                   const int* __restrict__ vmask, const int* __restrict__ tmask,
                   const float* __restrict__ vaw, const float* __restrict__ taw,
                   short* __restrict__ Av, short* __restrict__ At,
                   float* __restrict__ Onm_v, float* __restrict__ Onm_t) {
  __shared__ float tile[16 * 260];
  __shared__ int msk[2][256];
  const int tid = threadIdx.x;
  const int b = blockIdx.y, t0 = blockIdx.x * 16;
  const int r = tid >> 4, seg = tid & 15;
  msk[0][tid] = vmask[b * 256 + tid];
  msk[1][tid] = tmask[b * 256 + tid];
  __syncthreads();
  const float sv = 1.f / (1.f + __expf(-vaw[0]));
  const float st = 1.f / (1.f + __expf(-taw[0]));
  const long long off = ((long long)b * T_DIM + t0 + r) * N_DIM + seg * 16;

  short8 lv0 = *(const short8*)&Lv[off];
  short8 lv1 = *(const short8*)&Lv[off + 8];
  short8 lt0 = *(const short8*)&Lt[off];
  short8 lt1 = *(const short8*)&Lt[off + 8];
  float cv[16], ct[16];
  #pragma unroll
  for (int i = 0; i < 8; ++i) {
    float a0 = bf2f(lv0[i]), b0 = bf2f(lt0[i]);
    float a1 = bf2f(lv1[i]), b1 = bf2f(lt1[i]);
    cv[i]     = a0 + sv * b0;  ct[i]     = b0 + st * a0;
    cv[8 + i] = a1 + sv * b1;  ct[8 + i] = b1 + st * a1;
  }

#define EMIT_DOMAIN(CVAL, DI, AOUT, ONM) do {                                   \
    const int4 mA = *(const int4*)&msk[DI][seg * 16 + 0];                       \
    const int4 mB = *(const int4*)&msk[DI][seg * 16 + 4];                       \
    const int4 mC = *(const int4*)&msk[DI][seg * 16 + 8];                       \
    const int4 mD = *(const int4*)&msk[DI][seg * 16 + 12];                      \
    const int mk[16] = {mA.x, mA.y, mA.z, mA.w, mB.x, mB.y, mB.z, mB.w,         \
                        mC.x, mC.y, mC.z, mC.w, mD.x, mD.y, mD.z, mD.w};        \
    float mx = -3.4e38f;                                                        \
    _Pragma("unroll")                                                           \
    for (int q = 0; q < 16; ++q) if (mk[q] > 0) mx = fmaxf(mx, CVAL[q]);        \
    _Pragma("unroll")                                                           \
    for (int sh = 1; sh < 16; sh <<= 1) mx = fmaxf(mx, __shfl_xor(mx, sh));     \
    float ev[16]; float ssum = 0.f;                                             \
    _Pragma("unroll")                                                           \
    for (int q = 0; q < 16; ++q) {                                              \
      ev[q] = (mk[q] > 0) ? __expf(CVAL[q] - mx) : 0.f; ssum += ev[q];          \
    }                                                                           \
    _Pragma("unroll")                                                           \
    for (int sh = 1; sh < 16; sh <<= 1) ssum += __shfl_xor(ssum, sh);           \
    const float inv = 1.f / ssum;                                               \
    short8 o0, o1;                                                              \
    _Pragma("unroll")                                                           \
    for (int q = 0; q < 8; ++q) {                                               \
      o0[q] = cvt_bf16(ev[q] * inv); o1[q] = cvt_bf16(ev[8 + q] * inv);         \
    }                                                                           \
    *(short8*)&AOUT[off] = o0; *(short8*)&AOUT[off + 8] = o1;                   \
    _Pragma("unroll")                                                           \
    for (int q = 0; q < 4; ++q) {                                               \
      f32x4 tv; tv[0] = CVAL[q * 4]; tv[1] = CVAL[q * 4 + 1];                   \
      tv[2] = CVAL[q * 4 + 2]; tv[3] = CVAL[q * 4 + 3];                         \
      *(f32x4*)&tile[r * 260 + seg * 16 + q * 4] = tv;                          \
    }                                                                           \
    __syncthreads();                                                            \
    {                                                                           \
      float* obase = &ONM[((long long)b * N_DIM + tid) * T_DIM + t0];           \
      _Pragma("unroll")                                                         \
      for (int g = 0; g < 4; ++g) {                                             \
        f32x4 wv;                                                               \
        wv[0] = tile[(4 * g + 0) * 260 + tid];                                  \
        wv[1] = tile[(4 * g + 1) * 260 + tid];                                  \
        wv[2] = tile[(4 * g + 2) * 260 + tid];                                  \
        wv[3] = tile[(4 * g + 3) * 260 + tid];                                  \
        *(f32x4*)&obase[4 * g] = wv;                                            \
      }                                                                         \
    }                                                                           \
    __syncthreads();                                                            \
  } while (0)

  EMIT_DOMAIN(cv, 0, Av, Onm_v);
  EMIT_DOMAIN(ct, 1, At, Onm_t);
#undef EMIT_DOMAIN
}

// ---------------------------------------------------------------------------
// Task heads
// ---------------------------------------------------------------------------
__global__ __launch_bounds__(1024)
void task_kernel(const float* __restrict__ vtask, const float* __restrict__ ttask,
                 const float* __restrict__ vtw, const float* __restrict__ vtb,
                 const float* __restrict__ ttw, const float* __restrict__ ttb,
                 float* __restrict__ out_v, float* __restrict__ out_t) {
  const int wave = threadIdx.x >> 6;
  const int lane = threadIdx.x & 63;
  const int dom = wave >> 3;
  const int b   = wave & 7;
  const float* task = dom ? ttask : vtask;
  const float* tw   = dom ? ttw : vtw;
  const float  tb   = (dom ? ttb : vtb)[0];
  float* o = dom ? out_t : out_v;
  for (int k = 0; k < NT_DIM; ++k) {
    const float* row = task + ((long long)k * B_DIM + b) * H_DIM;
    float s = 0.f;
    for (int c = lane; c < H_DIM; c += 64) s += row[c] * tw[c];
    #pragma unroll
    for (int d = 32; d > 0; d >>= 1) s += __shfl_xor(s, d);
    if (lane == 0) o[k * B_DIM + b] = s + tb;
  }
}

// ---------------------------------------------------------------------------
extern "C" void kernel_launch(void* const* d_in, const int* in_sizes, int n_in,
                              void* d_out, int out_size, void* d_ws, size_t ws_size,
                              hipStream_t stream) {
  const float* v_action = (const float*)d_in[0];
  const float* v_frame  = (const float*)d_in[1];
  const float* v_task   = (const float*)d_in[2];
  const int*   v_mask   = (const int*)d_in[3];
  const float* t_action = (const float*)d_in[4];
  const float* t_frame  = (const float*)d_in[5];
  const float* t_task   = (const float*)d_in[6];
  const int*   t_mask   = (const int*)d_in[7];
  const float* v_aw = (const float*)d_in[16];
  const float* t_aw = (const float*)d_in[17];
  const float* v_tw = (const float*)d_in[18];
  const float* v_tb = (const float*)d_in[19];
  const float* t_tw = (const float*)d_in[20];
  const float* t_tb = (const float*)d_in[21];

  const long long TBH = (long long)T_DIM * B_DIM * H_DIM;
  const long long BTN = (long long)B_DIM * T_DIM * N_DIM;
  const long long NBH = (long long)N_DIM * B_DIM * H_DIM;
  const long long WS  = (long long)H_DIM * H_DIM;

  float* out = (float*)d_out;
  float* out_v   = out;
  float* out_t   = out + TBH;
  float* out_vnm = out + 2 * TBH;
  float* out_tnm = out + 2 * TBH + BTN;
  float* out_vta = out + 2 * TBH + 2 * BTN;
  float* out_tta = out_vta + NT_DIM * B_DIM;

  char* w = (char*)d_ws;
  auto alloc = [&](long long bytes) {
    char* p = w; w += (bytes + 255) & ~255LL; return p;
  };
  short* WT  = (short*)alloc(8 * WS * 2);
  short* Qv  = (short*)alloc(TBH * 2);      // reused as midv
  short* Qt  = (short*)alloc(TBH * 2);      // reused as midt
  short* KVv = (short*)alloc(2048LL * 1024 * 2);
  short* KVt = (short*)alloc(2048LL * 1024 * 2);
  short* VTv = (short*)alloc(NBH * 2);
  short* VTt = (short*)alloc(NBH * 2);
  short* Av  = (short*)alloc(BTN * 2);
  short* At  = (short*)alloc(BTN * 2);
  short* Lv  = (short*)alloc(BTN * 2);
  short* Lt  = (short*)alloc(BTN * 2);
  short* midv = Qv;
  short* midt = Qt;

  const float rsq = 0.044194173824159216f;  // 1/sqrt(512)

  // 1. weight transpose + cvt
  WSrc ws8;
  for (int i = 0; i < 8; ++i) ws8.p[i] = (const float*)d_in[8 + i];
  wtrans_kernel<<<dim3(16, 16, 8), dim3(32, 8), 0, stream>>>(ws8, WT);

  // 2. Q projections (f32 A), both domains
  {
    GP p = {{v_frame, t_frame}, {WT + 0 * WS, WT + 4 * WS}, {Qv, Qt}, {nullptr, nullptr}};
    gemm_tn<float, short, false><<<dim3(256, 4, 2), dim3(256), 0, stream>>>(
        p, 0, 0LL, H_DIM, 0LL, H_DIM, 0LL, H_DIM, 512, 1.f);
  }

  // 3. merged K|V projections (Wk^T,Wv^T adjacent in WT), both domains
  {
    GP p = {{v_action, t_action}, {WT + 1 * WS, WT + 5 * WS}, {KVv, KVt}, {nullptr, nullptr}};
    gemm_tn<float, short, false><<<dim3(16, 8, 2), dim3(256), 0, stream>>>(
        p, 0, 0LL, H_DIM, 0LL, H_DIM, 0LL, 1024, 512, 1.f);
  }

  // 4. V transpose -> VT[b][h][n]
  vtrans_kernel<<<dim3(16, 8, 16), dim3(32, 8), 0, stream>>>(KVv, KVt, VTv, VTt);

  // 5. logits (bf16 out) [B,T,N], both domains (z = dom*8 + b)
  {
    GP p = {{Qv, Qt}, {KVv, KVt}, {Lv, Lt}, {nullptr, nullptr}};
    gemm_tn<short, short, false><<<dim3(32, 2, 16), dim3(256), 0, stream>>>(
        p, 3, 512LL, B_DIM * H_DIM, 1024LL, 8192,
        (long long)T_DIM * N_DIM, N_DIM, 512, rsq);
  }

  // 6. fused combine + softmax + nomask-transpose (writes out_nm directly)
  softmax_fused<<<dim3(T_DIM / 16, B_DIM), dim3(256), 0, stream>>>(
      Lv, Lt, v_mask, t_mask, v_aw, t_aw, Av, At, out_vnm, out_tnm);

  // 7. attn @ V, both domains
  {
    GP p = {{Av, At}, {VTv, VTt}, {midv, midt}, {nullptr, nullptr}};
    gemm_tn<short, short, false><<<dim3(32, 4, 16), dim3(256), 0, stream>>>(
        p, 3, (long long)T_DIM * N_DIM, N_DIM, (long long)H_DIM * N_DIM, N_DIM,
        512LL, B_DIM * H_DIM, 256, 1.f);
  }

  // 8. output projection + residual, both domains
  {
    GP p = {{midv, midt}, {WT + 3 * WS, WT + 7 * WS}, {out_v, out_t}, {v_frame, t_frame}};
    gemm_tn<short, float, true><<<dim3(256, 4, 2), dim3(256), 0, stream>>>(
        p, 0, 0LL, H_DIM, 0LL, H_DIM, 0LL, H_DIM, 512, 1.f);
  }

  // 9. task heads
  task_kernel<<<dim3(1), dim3(1024), 0, stream>>>(
      v_task, t_task, v_tw, v_tb, t_tw, t_tb, out_vta, out_tta);
}

// Round 5
// 336.925 us; speedup vs baseline: 1.4269x; 1.0800x over previous
//
#include <hip/hip_runtime.h>
#include <hip/hip_bf16.h>
#include <cstddef>
#include <cstdint>

#define T_DIM 4096
#define B_DIM 8
#define N_DIM 256
#define H_DIM 512
#define NT_DIM 5

typedef __attribute__((ext_vector_type(8))) short short8;
typedef __attribute__((ext_vector_type(4))) float f32x4;

__device__ __forceinline__ short cvt_bf16(float f) {
  __hip_bfloat16 h = __float2bfloat16(f);   // HW cvt path (m240)
  union { __hip_bfloat16 h; short s; } u; u.h = h; return u.s;
}
__device__ __forceinline__ float bf2f(short s) {
  union { uint32_t u; float f; } v; v.u = ((uint32_t)(uint16_t)s) << 16;
  return v.f;
}

// async global->LDS, 16B/lane; LDS dest = wave-uniform base + lane*16
typedef __attribute__((address_space(1))) const void gvoid_t;
typedef __attribute__((address_space(3))) void lvoid_t;
__device__ __forceinline__ void gl_lds16(const void* g, void* lds_wave_base) {
  __builtin_amdgcn_global_load_lds((gvoid_t*)(uintptr_t)g,
                                   (lvoid_t*)(uint32_t)(uintptr_t)lds_wave_base,
                                   16, 0, 0);
}

// dual-domain pointer set: dom = blockIdx.z >> zlog, zz = blockIdx.z & mask
struct GP {
  const void* A[2];
  const short* B[2];
  void* C[2];
  const float* R[2];
};

// ---------------------------------------------------------------------------
// TN GEMM: C[m,n] = scale * sum_k A[m,k] * Bt[n,k]  (+ Res[m,n])
// 128x128 tile, 4 waves, BK=32, 16x16x32 bf16 MFMA, DOUBLE-BUFFERED:
// stage(next) issued BEFORE compute(cur) so HBM latency hides under MFMA
// (T3 minimum 2-phase). bf16 A/B staged via global_load_lds with both-sides
// XOR swizzle (rule 21); f32 A reg-prefetched (loads pre-compute, cvt+ds_write
// post-compute) into padded LDS [128][40].
// Epilogue: per-wave LDS restage (stride 68) -> coalesced dwordx4 IO, with
// Res loads software-pipelined one i-block ahead.
// ---------------------------------------------------------------------------
template<typename TA, typename TC, bool ADD_RES>
__global__ __launch_bounds__(256)
void gemm_tn(GP p, int zlog, long long a_bs, int lda,
             long long b_bs, int ldb, long long c_bs, int ldc,
             int K, float scale) {
  constexpr bool F32A = (sizeof(TA) == 4);
  constexpr int ASTR = F32A ? 40 : 32;
  constexpr int AB = 128 * ASTR * 2;     // bytes per A buffer
  constexpr int BB = 128 * 32 * 2;       // bytes per B buffer
  constexpr int HALF = AB + BB;
  constexpr int EPIB = 4 * 16 * 68 * 4;
  constexpr int SMEMB = (2 * HALF) > EPIB ? (2 * HALF) : EPIB;
  __shared__ __align__(16) char smem[SMEMB];

  const int tid  = threadIdx.x;
  const int lane = tid & 63;
  const int wave = tid >> 6;
  const int wr   = (wave >> 1) * 64;
  const int wc   = (wave & 1) * 64;
  const int lrow = lane & 15;
  const int kgrp = lane >> 4;

  const int dom = blockIdx.z >> zlog;
  const long long zz = blockIdx.z & ((1u << zlog) - 1u);

  const TA*    Abase = (const TA*)p.A[dom] + zz * a_bs + (long long)(blockIdx.x * 128) * lda;
  const short* Bbase = p.B[dom] + zz * b_bs + (long long)(blockIdx.y * 128) * ldb;

  // bf16 stage geometry: chunk c = 16 rows x 32 shorts (1 KiB), rows c*16..+15
  const int ch_r  = lane >> 2;
  const int swcol = ((lane & 3) ^ (ch_r & 3)) * 8;   // pre-swizzled source col
  // f32 reg-stage geometry
  const int srow = tid >> 1;
  const int scol = (tid & 1) * 16;

  f32x4 acc[4][4] = {};
  f32x4 pv[4];   // f32-A prefetch regs

  auto stageA_bf16 = [&](int bufoff, int k0) {
    short* As = (short*)(smem + bufoff);
    #pragma unroll
    for (int i = 0; i < 2; ++i) {
      const int c = wave + 4 * i;
      gl_lds16((const short*)Abase + (long long)(c * 16 + ch_r) * lda + k0 + swcol,
               &As[c * 512]);
    }
  };
  auto stageB = [&](int bufoff, int k0) {
    short* Bs = (short*)(smem + bufoff + AB);
    #pragma unroll
    for (int i = 0; i < 2; ++i) {
      const int c = wave + 4 * i;
      gl_lds16(Bbase + (long long)(c * 16 + ch_r) * ldb + k0 + swcol, &Bs[c * 512]);
    }
  };
  auto loadA_f32 = [&](int k0) {
    const float* gp = (const float*)Abase + (long long)srow * lda + k0 + scol;
    pv[0] = *(const f32x4*)(gp + 0);
    pv[1] = *(const f32x4*)(gp + 4);
    pv[2] = *(const f32x4*)(gp + 8);
    pv[3] = *(const f32x4*)(gp + 12);
  };
  auto writeA_f32 = [&](int bufoff) {
    short* As = (short*)(smem + bufoff);
    short8 s0, s1;
    #pragma unroll
    for (int e = 0; e < 4; ++e) {
      s0[e]     = cvt_bf16(pv[0][e]);
      s0[4 + e] = cvt_bf16(pv[1][e]);
      s1[e]     = cvt_bf16(pv[2][e]);
      s1[4 + e] = cvt_bf16(pv[3][e]);
    }
    *(short8*)&As[srow * ASTR + scol]     = s0;
    *(short8*)&As[srow * ASTR + scol + 8] = s1;
  };
  auto compute = [&](int bufoff) {
    short* As = (short*)(smem + bufoff);
    short* Bs = (short*)(smem + bufoff + AB);
    short8 af[4], bfr[4];
    const int u = kgrp ^ (lrow & 3);
    #pragma unroll
    for (int i = 0; i < 4; ++i) {
      const int row = wr + i * 16 + lrow;
      if constexpr (F32A) af[i] = *(const short8*)&As[row * ASTR + kgrp * 8];
      else                af[i] = *(const short8*)&As[row * 32 + u * 8];
    }
    #pragma unroll
    for (int j = 0; j < 4; ++j) {
      const int row = wc + j * 16 + lrow;
      bfr[j] = *(const short8*)&Bs[row * 32 + u * 8];
    }
    #pragma unroll
    for (int i = 0; i < 4; ++i)
      #pragma unroll
      for (int j = 0; j < 4; ++j)
        acc[i][j] = __builtin_amdgcn_mfma_f32_16x16x32_bf16(af[i], bfr[j], acc[i][j], 0, 0, 0);
  };

  // prologue: stage tile 0 into buffer 0
  if constexpr (F32A) { loadA_f32(0); writeA_f32(0); }
  else                stageA_bf16(0, 0);
  stageB(0, 0);
  __syncthreads();

  const int NT = K >> 5;
  int cur = 0;
  for (int t = 0; t < NT; ++t) {
    const int nxt = (cur ^ 1) * HALF;
    const bool more = (t + 1 < NT);
    if (more) {                       // issue next-tile staging BEFORE compute
      if constexpr (F32A) loadA_f32((t + 1) << 5);
      else                stageA_bf16(nxt, (t + 1) << 5);
      stageB(nxt, (t + 1) << 5);
    }
    compute(cur * HALF);
    if (more) {
      if constexpr (F32A) writeA_f32(nxt);
    }
    __syncthreads();                  // drains vmcnt/lgkm; next buffer ready
    cur ^= 1;
  }

  // ---- epilogue: LDS restage -> coalesced vector IO, Res pipelined ----
  __syncthreads();   // all waves done with LDS buffers
  float* myEp = (float*)smem + wave * (16 * 68);
  TC* Cd = (TC*)p.C[dom];
  const float* Res = p.R[dom];
  const long long cb = zz * c_bs;
  const int gm = blockIdx.x * 128 + wr;
  const int gn = blockIdx.y * 128 + wc;
  const int er = lane >> 2;          // read-back row 0..15
  const int ec = (lane & 3) * 16;    // read-back col base

  f32x4 resA[4], resB[4];
  if constexpr (ADD_RES) {
    const long long b0 = cb + (long long)(gm + er) * ldc + gn + ec;
    #pragma unroll
    for (int q = 0; q < 4; ++q) resA[q] = *(const f32x4*)&Res[b0 + q * 4];
  }

  #pragma unroll
  for (int i = 0; i < 4; ++i) {
    if constexpr (ADD_RES) {
      if (i < 3) {                   // prefetch next i-block's residual
        const long long bn = cb + (long long)(gm + (i + 1) * 16 + er) * ldc + gn + ec;
        #pragma unroll
        for (int q = 0; q < 4; ++q) resB[q] = *(const f32x4*)&Res[bn + q * 4];
      }
    }
    #pragma unroll
    for (int j = 0; j < 4; ++j)
      #pragma unroll
      for (int r = 0; r < 4; ++r)
        myEp[(kgrp * 4 + r) * 68 + j * 16 + lrow] = acc[i][j][r];
    float vals[16];
    #pragma unroll
    for (int q = 0; q < 4; ++q) {
      f32x4 t4 = *(const f32x4*)&myEp[er * 68 + ec + q * 4];
      vals[q * 4 + 0] = t4[0]; vals[q * 4 + 1] = t4[1];
      vals[q * 4 + 2] = t4[2]; vals[q * 4 + 3] = t4[3];
    }
    const int row_g = gm + i * 16 + er;
    const long long base = cb + (long long)row_g * ldc + gn + ec;
    if constexpr (sizeof(TC) == 2) {
      short8 s0, s1;
      #pragma unroll
      for (int e = 0; e < 8; ++e) {
        s0[e] = cvt_bf16(vals[e] * scale);
        s1[e] = cvt_bf16(vals[8 + e] * scale);
      }
      *(short8*)&Cd[base]     = s0;
      *(short8*)&Cd[base + 8] = s1;
    } else {
      #pragma unroll
      for (int q = 0; q < 4; ++q) {
        f32x4 o;
        #pragma unroll
        for (int e = 0; e < 4; ++e) o[e] = vals[q * 4 + e] * scale;
        if constexpr (ADD_RES) {
          #pragma unroll
          for (int e = 0; e < 4; ++e) o[e] += resA[q][e];
        }
        *(f32x4*)&Cd[base + q * 4] = o;
      }
    }
    if constexpr (ADD_RES) {
      #pragma unroll
      for (int q = 0; q < 4; ++q) resA[q] = resB[q];
    }
  }
}

// ---------------------------------------------------------------------------
// Weight transpose + cvt: WT[w][n][k] = bf16(W[w][k][n]), 8 matrices 512x512
// ---------------------------------------------------------------------------
struct WSrc { const float* p[8]; };

__global__ __launch_bounds__(256)
void wtrans_kernel(WSrc s, short* __restrict__ dst) {
  __shared__ float tile[32][33];
  const int w = blockIdx.z;
  const float* src = s.p[w];
  short* d = dst + (long long)w * H_DIM * H_DIM;
  const int tx = threadIdx.x, ty = threadIdx.y;
  const int n0 = blockIdx.x * 32, k0 = blockIdx.y * 32;
  #pragma unroll
  for (int i = 0; i < 4; ++i)
    tile[ty + 8 * i][tx] = src[(long long)(k0 + ty + 8 * i) * H_DIM + n0 + tx];
  __syncthreads();
  #pragma unroll
  for (int i = 0; i < 4; ++i)
    d[(long long)(n0 + ty + 8 * i) * H_DIM + k0 + tx] = cvt_bf16(tile[tx][ty + 8 * i]);
}

// ---------------------------------------------------------------------------
// V transpose from merged KV: VT[b][h][n] = KV[(n*8+b)*1024 + 512 + h]
// ---------------------------------------------------------------------------
__global__ __launch_bounds__(256)
void vtrans_kernel(const short* __restrict__ KVv, const short* __restrict__ KVt,
                   short* __restrict__ VTv, short* __restrict__ VTt) {
  __shared__ short tile[32][33];
  const int z = blockIdx.z;
  const int dom = z >> 3, b = z & 7;
  const short* src = (dom ? KVt : KVv) + b * 1024 + 512;
  short* dst = (dom ? VTt : VTv) + (long long)b * H_DIM * N_DIM;
  const int tx = threadIdx.x, ty = threadIdx.y;
  const int h0 = blockIdx.x * 32, n0 = blockIdx.y * 32;
  #pragma unroll
  for (int i = 0; i < 4; ++i)
    tile[ty + 8 * i][tx] = src[(long long)(n0 + ty + 8 * i) * 8192 + h0 + tx];
  __syncthreads();
  #pragma unroll
  for (int i = 0; i < 4; ++i)
    dst[(long long)(h0 + ty + 8 * i) * N_DIM + n0 + tx] = tile[tx][ty + 8 * i];
}

// ---------------------------------------------------------------------------
// Fused: combine + masked softmax + bf16 attn + nomask transpose to d_out.
// Grid (T/16, B), 256 thr. r=tid>>4 (t-row), seg=tid&15 (16-col slice).
// ---------------------------------------------------------------------------
__global__ __launch_bounds__(256)
void softmax_fused(const short* __restrict__ Lv, const short* __restrict__ Lt,
                   const int* __restrict__ vmask, const int* __restrict__ tmask,
                   const float* __restrict__ vaw, const float* __restrict__ taw,
                   short* __restrict__ Av, short* __restrict__ At,
                   float* __restrict__ Onm_v, float* __restrict__ Onm_t) {
  __shared__ float tile[16 * 260];
  __shared__ int msk[2][256];
  const int tid = threadIdx.x;
  const int b = blockIdx.y, t0 = blockIdx.x * 16;
  const int r = tid >> 4, seg = tid & 15;
  msk[0][tid] = vmask[b * 256 + tid];
  msk[1][tid] = tmask[b * 256 + tid];
  __syncthreads();
  const float sv = 1.f / (1.f + __expf(-vaw[0]));
  const float st = 1.f / (1.f + __expf(-taw[0]));
  const long long off = ((long long)b * T_DIM + t0 + r) * N_DIM + seg * 16;

  short8 lv0 = *(const short8*)&Lv[off];
  short8 lv1 = *(const short8*)&Lv[off + 8];
  short8 lt0 = *(const short8*)&Lt[off];
  short8 lt1 = *(const short8*)&Lt[off + 8];
  float cv[16], ct[16];
  #pragma unroll
  for (int i = 0; i < 8; ++i) {
    float a0 = bf2f(lv0[i]), b0 = bf2f(lt0[i]);
    float a1 = bf2f(lv1[i]), b1 = bf2f(lt1[i]);
    cv[i]     = a0 + sv * b0;  ct[i]     = b0 + st * a0;
    cv[8 + i] = a1 + sv * b1;  ct[8 + i] = b1 + st * a1;
  }

#define EMIT_DOMAIN(CVAL, DI, AOUT, ONM) do {                                   \
    const int4 mA = *(const int4*)&msk[DI][seg * 16 + 0];                       \
    const int4 mB = *(const int4*)&msk[DI][seg * 16 + 4];                       \
    const int4 mC = *(const int4*)&msk[DI][seg * 16 + 8];                       \
    const int4 mD = *(const int4*)&msk[DI][seg * 16 + 12];                      \
    const int mk[16] = {mA.x, mA.y, mA.z, mA.w, mB.x, mB.y, mB.z, mB.w,         \
                        mC.x, mC.y, mC.z, mC.w, mD.x, mD.y, mD.z, mD.w};        \
    float mx = -3.4e38f;                                                        \
    _Pragma("unroll")                                                           \
    for (int q = 0; q < 16; ++q) if (mk[q] > 0) mx = fmaxf(mx, CVAL[q]);        \
    _Pragma("unroll")                                                           \
    for (int sh = 1; sh < 16; sh <<= 1) mx = fmaxf(mx, __shfl_xor(mx, sh));     \
    float ev[16]; float ssum = 0.f;                                             \
    _Pragma("unroll")                                                           \
    for (int q = 0; q < 16; ++q) {                                              \
      ev[q] = (mk[q] > 0) ? __expf(CVAL[q] - mx) : 0.f; ssum += ev[q];          \
    }                                                                           \
    _Pragma("unroll")                                                           \
    for (int sh = 1; sh < 16; sh <<= 1) ssum += __shfl_xor(ssum, sh);           \
    const float inv = 1.f / ssum;                                               \
    short8 o0, o1;                                                              \
    _Pragma("unroll")                                                           \
    for (int q = 0; q < 8; ++q) {                                               \
      o0[q] = cvt_bf16(ev[q] * inv); o1[q] = cvt_bf16(ev[8 + q] * inv);         \
    }                                                                           \
    *(short8*)&AOUT[off] = o0; *(short8*)&AOUT[off + 8] = o1;                   \
    _Pragma("unroll")                                                           \
    for (int q = 0; q < 4; ++q) {                                               \
      f32x4 tv; tv[0] = CVAL[q * 4]; tv[1] = CVAL[q * 4 + 1];                   \
      tv[2] = CVAL[q * 4 + 2]; tv[3] = CVAL[q * 4 + 3];                         \
      *(f32x4*)&tile[r * 260 + seg * 16 + q * 4] = tv;                          \
    }                                                                           \
    __syncthreads();                                                            \
    {                                                                           \
      float* obase = &ONM[((long long)b * N_DIM + tid) * T_DIM + t0];           \
      _Pragma("unroll")                                                         \
      for (int g = 0; g < 4; ++g) {                                             \
        f32x4 wv;                                                               \
        wv[0] = tile[(4 * g + 0) * 260 + tid];                                  \
        wv[1] = tile[(4 * g + 1) * 260 + tid];                                  \
        wv[2] = tile[(4 * g + 2) * 260 + tid];                                  \
        wv[3] = tile[(4 * g + 3) * 260 + tid];                                  \
        *(f32x4*)&obase[4 * g] = wv;                                            \
      }                                                                         \
    }                                                                           \
    __syncthreads();                                                            \
  } while (0)

  EMIT_DOMAIN(cv, 0, Av, Onm_v);
  EMIT_DOMAIN(ct, 1, At, Onm_t);
#undef EMIT_DOMAIN
}

// ---------------------------------------------------------------------------
// Task heads
// ---------------------------------------------------------------------------
__global__ __launch_bounds__(1024)
void task_kernel(const float* __restrict__ vtask, const float* __restrict__ ttask,
                 const float* __restrict__ vtw, const float* __restrict__ vtb,
                 const float* __restrict__ ttw, const float* __restrict__ ttb,
                 float* __restrict__ out_v, float* __restrict__ out_t) {
  const int wave = threadIdx.x >> 6;
  const int lane = threadIdx.x & 63;
  const int dom = wave >> 3;
  const int b   = wave & 7;
  const float* task = dom ? ttask : vtask;
  const float* tw   = dom ? ttw : vtw;
  const float  tb   = (dom ? ttb : vtb)[0];
  float* o = dom ? out_t : out_v;
  for (int k = 0; k < NT_DIM; ++k) {
    const float* row = task + ((long long)k * B_DIM + b) * H_DIM;
    float s = 0.f;
    for (int c = lane; c < H_DIM; c += 64) s += row[c] * tw[c];
    #pragma unroll
    for (int d = 32; d > 0; d >>= 1) s += __shfl_xor(s, d);
    if (lane == 0) o[k * B_DIM + b] = s + tb;
  }
}

// ---------------------------------------------------------------------------
extern "C" void kernel_launch(void* const* d_in, const int* in_sizes, int n_in,
                              void* d_out, int out_size, void* d_ws, size_t ws_size,
                              hipStream_t stream) {
  const float* v_action = (const float*)d_in[0];
  const float* v_frame  = (const float*)d_in[1];
  const float* v_task   = (const float*)d_in[2];
  const int*   v_mask   = (const int*)d_in[3];
  const float* t_action = (const float*)d_in[4];
  const float* t_frame  = (const float*)d_in[5];
  const float* t_task   = (const float*)d_in[6];
  const int*   t_mask   = (const int*)d_in[7];
  const float* v_aw = (const float*)d_in[16];
  const float* t_aw = (const float*)d_in[17];
  const float* v_tw = (const float*)d_in[18];
  const float* v_tb = (const float*)d_in[19];
  const float* t_tw = (const float*)d_in[20];
  const float* t_tb = (const float*)d_in[21];

  const long long TBH = (long long)T_DIM * B_DIM * H_DIM;
  const long long BTN = (long long)B_DIM * T_DIM * N_DIM;
  const long long NBH = (long long)N_DIM * B_DIM * H_DIM;
  const long long WS  = (long long)H_DIM * H_DIM;

  float* out = (float*)d_out;
  float* out_v   = out;
  float* out_t   = out + TBH;
  float* out_vnm = out + 2 * TBH;
  float* out_tnm = out + 2 * TBH + BTN;
  float* out_vta = out + 2 * TBH + 2 * BTN;
  float* out_tta = out_vta + NT_DIM * B_DIM;

  char* w = (char*)d_ws;
  auto alloc = [&](long long bytes) {
    char* p = w; w += (bytes + 255) & ~255LL; return p;
  };
  short* WT  = (short*)alloc(8 * WS * 2);
  short* Qv  = (short*)alloc(TBH * 2);      // reused as midv
  short* Qt  = (short*)alloc(TBH * 2);      // reused as midt
  short* KVv = (short*)alloc(2048LL * 1024 * 2);
  short* KVt = (short*)alloc(2048LL * 1024 * 2);
  short* VTv = (short*)alloc(NBH * 2);
  short* VTt = (short*)alloc(NBH * 2);
  short* Av  = (short*)alloc(BTN * 2);
  short* At  = (short*)alloc(BTN * 2);
  short* Lv  = (short*)alloc(BTN * 2);
  short* Lt  = (short*)alloc(BTN * 2);
  short* midv = Qv;
  short* midt = Qt;

  const float rsq = 0.044194173824159216f;  // 1/sqrt(512)

  // 1. weight transpose + cvt
  WSrc ws8;
  for (int i = 0; i < 8; ++i) ws8.p[i] = (const float*)d_in[8 + i];
  wtrans_kernel<<<dim3(16, 16, 8), dim3(32, 8), 0, stream>>>(ws8, WT);

  // 2. Q projections (f32 A), both domains
  {
    GP p = {{v_frame, t_frame}, {WT + 0 * WS, WT + 4 * WS}, {Qv, Qt}, {nullptr, nullptr}};
    gemm_tn<float, short, false><<<dim3(256, 4, 2), dim3(256), 0, stream>>>(
        p, 0, 0LL, H_DIM, 0LL, H_DIM, 0LL, H_DIM, 512, 1.f);
  }

  // 3. merged K|V projections (Wk^T,Wv^T adjacent in WT), both domains
  {
    GP p = {{v_action, t_action}, {WT + 1 * WS, WT + 5 * WS}, {KVv, KVt}, {nullptr, nullptr}};
    gemm_tn<float, short, false><<<dim3(16, 8, 2), dim3(256), 0, stream>>>(
        p, 0, 0LL, H_DIM, 0LL, H_DIM, 0LL, 1024, 512, 1.f);
  }

  // 4. V transpose -> VT[b][h][n]
  vtrans_kernel<<<dim3(16, 8, 16), dim3(32, 8), 0, stream>>>(KVv, KVt, VTv, VTt);

  // 5. logits (bf16 out) [B,T,N], both domains (z = dom*8 + b)
  {
    GP p = {{Qv, Qt}, {KVv, KVt}, {Lv, Lt}, {nullptr, nullptr}};
    gemm_tn<short, short, false><<<dim3(32, 2, 16), dim3(256), 0, stream>>>(
        p, 3, 512LL, B_DIM * H_DIM, 1024LL, 8192,
        (long long)T_DIM * N_DIM, N_DIM, 512, rsq);
  }

  // 6. fused combine + softmax + nomask-transpose (writes out_nm directly)
  softmax_fused<<<dim3(T_DIM / 16, B_DIM), dim3(256), 0, stream>>>(
      Lv, Lt, v_mask, t_mask, v_aw, t_aw, Av, At, out_vnm, out_tnm);

  // 7. attn @ V, both domains
  {
    GP p = {{Av, At}, {VTv, VTt}, {midv, midt}, {nullptr, nullptr}};
    gemm_tn<short, short, false><<<dim3(32, 4, 16), dim3(256), 0, stream>>>(
        p, 3, (long long)T_DIM * N_DIM, N_DIM, (long long)H_DIM * N_DIM, N_DIM,
        512LL, B_DIM * H_DIM, 256, 1.f);
  }

  // 8. output projection + residual, both domains
  {
    GP p = {{midv, midt}, {WT + 3 * WS, WT + 7 * WS}, {out_v, out_t}, {v_frame, t_frame}};
    gemm_tn<short, float, true><<<dim3(256, 4, 2), dim3(256), 0, stream>>>(
        p, 0, 0LL, H_DIM, 0LL, H_DIM, 0LL, H_DIM, 512, 1.f);
  }

  // 9. task heads
  task_kernel<<<dim3(1), dim3(1024), 0, stream>>>(
      v_task, t_task, v_tw, v_tb, t_tw, t_tb, out_vta, out_tta);
}

// Round 6
// 292.310 us; speedup vs baseline: 1.6447x; 1.1526x over previous
//
#include <hip/hip_runtime.h>
#include <hip/hip_bf16.h>
#include <cstddef>
#include <cstdint>

#define T_DIM 4096
#define B_DIM 8
#define N_DIM 256
#define H_DIM 512
#define NT_DIM 5

typedef __attribute__((ext_vector_type(8))) short short8;
typedef __attribute__((ext_vector_type(4))) float f32x4;

__device__ __forceinline__ short cvt_bf16(float f) {
  __hip_bfloat16 h = __float2bfloat16(f);   // HW cvt path (m240)
  union { __hip_bfloat16 h; short s; } u; u.h = h; return u.s;
}
__device__ __forceinline__ float bf2f(short s) {
  union { uint32_t u; float f; } v; v.u = ((uint32_t)(uint16_t)s) << 16;
  return v.f;
}

// async global->LDS, 16B/lane; LDS dest = wave-uniform base + lane*16
typedef __attribute__((address_space(1))) const void gvoid_t;
typedef __attribute__((address_space(3))) void lvoid_t;
__device__ __forceinline__ void gl_lds16(const void* g, void* lds_wave_base) {
  __builtin_amdgcn_global_load_lds((gvoid_t*)(uintptr_t)g,
                                   (lvoid_t*)(uint32_t)(uintptr_t)lds_wave_base,
                                   16, 0, 0);
}

// dual-domain pointer set: dom = blockIdx.z >> zlog, zz = blockIdx.z & mask
struct GP {
  const void* A[2];
  const short* B[2];
  void* C[2];
  const float* R[2];
};

// ---------------------------------------------------------------------------
// TN GEMM: C[m,n] = scale * sum_k A[m,k] * Bt[n,k]  (+ Res[m,n])
// 128x128 tile, 4 waves, BK=32, 16x16x32 bf16 MFMA, double-buffered.
// bf16 A/B: global_load_lds + COUNTED vmcnt pipeline (T4):
//   barrier1 -> stage(next) -> s_waitcnt vmcnt(4) -> barrier2 -> compute
// so each tile's loads get a full iteration to land; never drains to 0.
// f32 A: round-5 proven structure (reg-prefetch + syncthreads).
// Epilogue: per-wave LDS restage (stride 68) -> coalesced dwordx4 IO,
// Res loads software-pipelined one i-block ahead.
// ---------------------------------------------------------------------------
template<typename TA, typename TC, bool ADD_RES>
__global__ __launch_bounds__(256)
void gemm_tn(GP p, int zlog, long long a_bs, int lda,
             long long b_bs, int ldb, long long c_bs, int ldc,
             int K, float scale) {
  constexpr bool F32A = (sizeof(TA) == 4);
  constexpr int ASTR = F32A ? 40 : 32;
  constexpr int AB = 128 * ASTR * 2;     // bytes per A buffer
  constexpr int BB = 128 * 32 * 2;       // bytes per B buffer
  constexpr int HALF = AB + BB;
  constexpr int EPIB = 4 * 16 * 68 * 4;
  constexpr int SMEMB = (2 * HALF) > EPIB ? (2 * HALF) : EPIB;
  __shared__ __align__(16) char smem[SMEMB];

  const int tid  = threadIdx.x;
  const int lane = tid & 63;
  const int wave = tid >> 6;
  const int wr   = (wave >> 1) * 64;
  const int wc   = (wave & 1) * 64;
  const int lrow = lane & 15;
  const int kgrp = lane >> 4;

  const int dom = blockIdx.z >> zlog;
  const long long zz = blockIdx.z & ((1u << zlog) - 1u);

  const TA*    Abase = (const TA*)p.A[dom] + zz * a_bs + (long long)(blockIdx.x * 128) * lda;
  const short* Bbase = p.B[dom] + zz * b_bs + (long long)(blockIdx.y * 128) * ldb;

  // bf16 stage geometry: chunk c = 16 rows x 32 shorts (1 KiB)
  const int ch_r  = lane >> 2;
  const int swcol = ((lane & 3) ^ (ch_r & 3)) * 8;   // pre-swizzled source col
  // f32 reg-stage geometry
  const int srow = tid >> 1;
  const int scol = (tid & 1) * 16;

  f32x4 acc[4][4] = {};
  f32x4 pv[4];   // f32-A prefetch regs

  auto stageA_bf16 = [&](int bufoff, int k0) {
    short* As = (short*)(smem + bufoff);
    #pragma unroll
    for (int i = 0; i < 2; ++i) {
      const int c = wave + 4 * i;
      gl_lds16((const short*)Abase + (long long)(c * 16 + ch_r) * lda + k0 + swcol,
               &As[c * 512]);
    }
  };
  auto stageB = [&](int bufoff, int k0) {
    short* Bs = (short*)(smem + bufoff + AB);
    #pragma unroll
    for (int i = 0; i < 2; ++i) {
      const int c = wave + 4 * i;
      gl_lds16(Bbase + (long long)(c * 16 + ch_r) * ldb + k0 + swcol, &Bs[c * 512]);
    }
  };
  auto loadA_f32 = [&](int k0) {
    const float* gp = (const float*)Abase + (long long)srow * lda + k0 + scol;
    pv[0] = *(const f32x4*)(gp + 0);
    pv[1] = *(const f32x4*)(gp + 4);
    pv[2] = *(const f32x4*)(gp + 8);
    pv[3] = *(const f32x4*)(gp + 12);
  };
  auto writeA_f32 = [&](int bufoff) {
    short* As = (short*)(smem + bufoff);
    short8 s0, s1;
    #pragma unroll
    for (int e = 0; e < 4; ++e) {
      s0[e]     = cvt_bf16(pv[0][e]);
      s0[4 + e] = cvt_bf16(pv[1][e]);
      s1[e]     = cvt_bf16(pv[2][e]);
      s1[4 + e] = cvt_bf16(pv[3][e]);
    }
    *(short8*)&As[srow * ASTR + scol]     = s0;
    *(short8*)&As[srow * ASTR + scol + 8] = s1;
  };
  auto compute = [&](int bufoff) {
    short* As = (short*)(smem + bufoff);
    short* Bs = (short*)(smem + bufoff + AB);
    short8 af[4], bfr[4];
    const int u = kgrp ^ (lrow & 3);
    #pragma unroll
    for (int i = 0; i < 4; ++i) {
      const int row = wr + i * 16 + lrow;
      if constexpr (F32A) af[i] = *(const short8*)&As[row * ASTR + kgrp * 8];
      else                af[i] = *(const short8*)&As[row * 32 + u * 8];
    }
    #pragma unroll
    for (int j = 0; j < 4; ++j) {
      const int row = wc + j * 16 + lrow;
      bfr[j] = *(const short8*)&Bs[row * 32 + u * 8];
    }
    #pragma unroll
    for (int i = 0; i < 4; ++i)
      #pragma unroll
      for (int j = 0; j < 4; ++j)
        acc[i][j] = __builtin_amdgcn_mfma_f32_16x16x32_bf16(af[i], bfr[j], acc[i][j], 0, 0, 0);
  };

  const int NT = K >> 5;
  if constexpr (F32A) {
    // round-5 proven structure
    loadA_f32(0); writeA_f32(0); stageB(0, 0);
    __syncthreads();
    int cur = 0;
    for (int t = 0; t < NT; ++t) {
      const int nxt = (cur ^ 1) * HALF;
      const bool more = (t + 1 < NT);
      if (more) { loadA_f32((t + 1) << 5); stageB(nxt, (t + 1) << 5); }
      compute(cur * HALF);
      if (more) writeA_f32(nxt);
      __syncthreads();
      cur ^= 1;
    }
  } else {
    // counted-vmcnt pipeline (T4)
    stageA_bf16(0, 0); stageB(0, 0);
    for (int t = 0; t < NT; ++t) {
      const int cb_ = (t & 1) * HALF;
      const int nb_ = ((t + 1) & 1) * HALF;
      __builtin_amdgcn_s_barrier();             // prev compute of nb_ done
      if (t + 1 < NT) { stageA_bf16(nb_, (t + 1) << 5); stageB(nb_, (t + 1) << 5); }
      __builtin_amdgcn_sched_barrier(0);
      if (t + 1 < NT) asm volatile("s_waitcnt vmcnt(4)" ::: "memory");
      else            asm volatile("s_waitcnt vmcnt(0)" ::: "memory");
      __builtin_amdgcn_sched_barrier(0);
      __builtin_amdgcn_s_barrier();             // cb_ staged for ALL waves
      __builtin_amdgcn_sched_barrier(0);
      compute(cb_);
    }
  }

  // ---- epilogue: LDS restage -> coalesced vector IO, Res pipelined ----
  __syncthreads();   // all waves done with LDS buffers
  float* myEp = (float*)smem + wave * (16 * 68);
  TC* Cd = (TC*)p.C[dom];
  const float* Res = p.R[dom];
  const long long cb = zz * c_bs;
  const int gm = blockIdx.x * 128 + wr;
  const int gn = blockIdx.y * 128 + wc;
  const int er = lane >> 2;          // read-back row 0..15
  const int ec = (lane & 3) * 16;    // read-back col base

  f32x4 resA[4], resB[4];
  if constexpr (ADD_RES) {
    const long long b0 = cb + (long long)(gm + er) * ldc + gn + ec;
    #pragma unroll
    for (int q = 0; q < 4; ++q) resA[q] = *(const f32x4*)&Res[b0 + q * 4];
  }

  #pragma unroll
  for (int i = 0; i < 4; ++i) {
    if constexpr (ADD_RES) {
      if (i < 3) {                   // prefetch next i-block's residual
        const long long bn = cb + (long long)(gm + (i + 1) * 16 + er) * ldc + gn + ec;
        #pragma unroll
        for (int q = 0; q < 4; ++q) resB[q] = *(const f32x4*)&Res[bn + q * 4];
      }
    }
    #pragma unroll
    for (int j = 0; j < 4; ++j)
      #pragma unroll
      for (int r = 0; r < 4; ++r)
        myEp[(kgrp * 4 + r) * 68 + j * 16 + lrow] = acc[i][j][r];
    float vals[16];
    #pragma unroll
    for (int q = 0; q < 4; ++q) {
      f32x4 t4 = *(const f32x4*)&myEp[er * 68 + ec + q * 4];
      vals[q * 4 + 0] = t4[0]; vals[q * 4 + 1] = t4[1];
      vals[q * 4 + 2] = t4[2]; vals[q * 4 + 3] = t4[3];
    }
    const int row_g = gm + i * 16 + er;
    const long long base = cb + (long long)row_g * ldc + gn + ec;
    if constexpr (sizeof(TC) == 2) {
      short8 s0, s1;
      #pragma unroll
      for (int e = 0; e < 8; ++e) {
        s0[e] = cvt_bf16(vals[e] * scale);
        s1[e] = cvt_bf16(vals[8 + e] * scale);
      }
      *(short8*)&Cd[base]     = s0;
      *(short8*)&Cd[base + 8] = s1;
    } else {
      #pragma unroll
      for (int q = 0; q < 4; ++q) {
        f32x4 o;
        #pragma unroll
        for (int e = 0; e < 4; ++e) o[e] = vals[q * 4 + e] * scale;
        if constexpr (ADD_RES) {
          #pragma unroll
          for (int e = 0; e < 4; ++e) o[e] += resA[q][e];
        }
        *(f32x4*)&Cd[base + q * 4] = o;
      }
    }
    if constexpr (ADD_RES) {
      #pragma unroll
      for (int q = 0; q < 4; ++q) resA[q] = resB[q];
    }
  }
}

// ---------------------------------------------------------------------------
// Weight transpose + cvt: WT[w][n][k] = bf16(W[w][k][n]), 8 matrices 512x512
// ---------------------------------------------------------------------------
struct WSrc { const float* p[8]; };

__global__ __launch_bounds__(256)
void wtrans_kernel(WSrc s, short* __restrict__ dst) {
  __shared__ float tile[32][33];
  const int w = blockIdx.z;
  const float* src = s.p[w];
  short* d = dst + (long long)w * H_DIM * H_DIM;
  const int tx = threadIdx.x, ty = threadIdx.y;
  const int n0 = blockIdx.x * 32, k0 = blockIdx.y * 32;
  #pragma unroll
  for (int i = 0; i < 4; ++i)
    tile[ty + 8 * i][tx] = src[(long long)(k0 + ty + 8 * i) * H_DIM + n0 + tx];
  __syncthreads();
  #pragma unroll
  for (int i = 0; i < 4; ++i)
    d[(long long)(n0 + ty + 8 * i) * H_DIM + k0 + tx] = cvt_bf16(tile[tx][ty + 8 * i]);
}

// ---------------------------------------------------------------------------
// Fused: combine + masked softmax + bf16 attn + nomask transpose to d_out.
// Grid (T/16, B), 256 thr. r=tid>>4 (t-row), seg=tid&15 (16-col slice).
// ---------------------------------------------------------------------------
__global__ __launch_bounds__(256)
void softmax_fused(const short* __restrict__ Lv, const short* __restrict__ Lt,
                   const int* __restrict__ vmask, const int* __restrict__ tmask,
                   const float* __restrict__ vaw, const float* __restrict__ taw,
                   short* __restrict__ Av, short* __restrict__ At,
                   float* __restrict__ Onm_v, float* __restrict__ Onm_t) {
  __shared__ float tile[16 * 260];
  __shared__ int msk[2][256];
  const int tid = threadIdx.x;
  const int b = blockIdx.y, t0 = blockIdx.x * 16;
  const int r = tid >> 4, seg = tid & 15;
  msk[0][tid] = vmask[b * 256 + tid];
  msk[1][tid] = tmask[b * 256 + tid];
  __syncthreads();
  const float sv = 1.f / (1.f + __expf(-vaw[0]));
  const float st = 1.f / (1.f + __expf(-taw[0]));
  const long long off = ((long long)b * T_DIM + t0 + r) * N_DIM + seg * 16;

  short8 lv0 = *(const short8*)&Lv[off];
  short8 lv1 = *(const short8*)&Lv[off + 8];
  short8 lt0 = *(const short8*)&Lt[off];
  short8 lt1 = *(const short8*)&Lt[off + 8];
  float cv[16], ct[16];
  #pragma unroll
  for (int i = 0; i < 8; ++i) {
    float a0 = bf2f(lv0[i]), b0 = bf2f(lt0[i]);
    float a1 = bf2f(lv1[i]), b1 = bf2f(lt1[i]);
    cv[i]     = a0 + sv * b0;  ct[i]     = b0 + st * a0;
    cv[8 + i] = a1 + sv * b1;  ct[8 + i] = b1 + st * a1;
  }

#define EMIT_DOMAIN(CVAL, DI, AOUT, ONM) do {                                   \
    const int4 mA = *(const int4*)&msk[DI][seg * 16 + 0];                       \
    const int4 mB = *(const int4*)&msk[DI][seg * 16 + 4];                       \
    const int4 mC = *(const int4*)&msk[DI][seg * 16 + 8];                       \
    const int4 mD = *(const int4*)&msk[DI][seg * 16 + 12];                      \
    const int mk[16] = {mA.x, mA.y, mA.z, mA.w, mB.x, mB.y, mB.z, mB.w,         \
                        mC.x, mC.y, mC.z, mC.w, mD.x, mD.y, mD.z, mD.w};        \
    float mx = -3.4e38f;                                                        \
    _Pragma("unroll")                                                           \
    for (int q = 0; q < 16; ++q) if (mk[q] > 0) mx = fmaxf(mx, CVAL[q]);        \
    _Pragma("unroll")                                                           \
    for (int sh = 1; sh < 16; sh <<= 1) mx = fmaxf(mx, __shfl_xor(mx, sh));     \
    float ev[16]; float ssum = 0.f;                                             \
    _Pragma("unroll")                                                           \
    for (int q = 0; q < 16; ++q) {                                              \
      ev[q] = (mk[q] > 0) ? __expf(CVAL[q] - mx) : 0.f; ssum += ev[q];          \
    }                                                                           \
    _Pragma("unroll")                                                           \
    for (int sh = 1; sh < 16; sh <<= 1) ssum += __shfl_xor(ssum, sh);           \
    const float inv = 1.f / ssum;                                               \
    short8 o0, o1;                                                              \
    _Pragma("unroll")                                                           \
    for (int q = 0; q < 8; ++q) {                                               \
      o0[q] = cvt_bf16(ev[q] * inv); o1[q] = cvt_bf16(ev[8 + q] * inv);         \
    }                                                                           \
    *(short8*)&AOUT[off] = o0; *(short8*)&AOUT[off + 8] = o1;                   \
    _Pragma("unroll")                                                           \
    for (int q = 0; q < 4; ++q) {                                               \
      f32x4 tv; tv[0] = CVAL[q * 4]; tv[1] = CVAL[q * 4 + 1];                   \
      tv[2] = CVAL[q * 4 + 2]; tv[3] = CVAL[q * 4 + 3];                         \
      *(f32x4*)&tile[r * 260 + seg * 16 + q * 4] = tv;                          \
    }                                                                           \
    __syncthreads();                                                            \
    {                                                                           \
      float* obase = &ONM[((long long)b * N_DIM + tid) * T_DIM + t0];           \
      _Pragma("unroll")                                                         \
      for (int g = 0; g < 4; ++g) {                                             \
        f32x4 wv;                                                               \
        wv[0] = tile[(4 * g + 0) * 260 + tid];                                  \
        wv[1] = tile[(4 * g + 1) * 260 + tid];                                  \
        wv[2] = tile[(4 * g + 2) * 260 + tid];                                  \
        wv[3] = tile[(4 * g + 3) * 260 + tid];                                  \
        *(f32x4*)&obase[4 * g] = wv;                                            \
      }                                                                         \
    }                                                                           \
    __syncthreads();                                                            \
  } while (0)

  EMIT_DOMAIN(cv, 0, Av, Onm_v);
  EMIT_DOMAIN(ct, 1, At, Onm_t);
#undef EMIT_DOMAIN
}

// ---------------------------------------------------------------------------
// Task heads
// ---------------------------------------------------------------------------
__global__ __launch_bounds__(1024)
void task_kernel(const float* __restrict__ vtask, const float* __restrict__ ttask,
                 const float* __restrict__ vtw, const float* __restrict__ vtb,
                 const float* __restrict__ ttw, const float* __restrict__ ttb,
                 float* __restrict__ out_v, float* __restrict__ out_t) {
  const int wave = threadIdx.x >> 6;
  const int lane = threadIdx.x & 63;
  const int dom = wave >> 3;
  const int b   = wave & 7;
  const float* task = dom ? ttask : vtask;
  const float* tw   = dom ? ttw : vtw;
  const float  tb   = (dom ? ttb : vtb)[0];
  float* o = dom ? out_t : out_v;
  for (int k = 0; k < NT_DIM; ++k) {
    const float* row = task + ((long long)k * B_DIM + b) * H_DIM;
    float s = 0.f;
    for (int c = lane; c < H_DIM; c += 64) s += row[c] * tw[c];
    #pragma unroll
    for (int d = 32; d > 0; d >>= 1) s += __shfl_xor(s, d);
    if (lane == 0) o[k * B_DIM + b] = s + tb;
  }
}

// ---------------------------------------------------------------------------
extern "C" void kernel_launch(void* const* d_in, const int* in_sizes, int n_in,
                              void* d_out, int out_size, void* d_ws, size_t ws_size,
                              hipStream_t stream) {
  const float* v_action = (const float*)d_in[0];
  const float* v_frame  = (const float*)d_in[1];
  const float* v_task   = (const float*)d_in[2];
  const int*   v_mask   = (const int*)d_in[3];
  const float* t_action = (const float*)d_in[4];
  const float* t_frame  = (const float*)d_in[5];
  const float* t_task   = (const float*)d_in[6];
  const int*   t_mask   = (const int*)d_in[7];
  const float* v_aw = (const float*)d_in[16];
  const float* t_aw = (const float*)d_in[17];
  const float* v_tw = (const float*)d_in[18];
  const float* v_tb = (const float*)d_in[19];
  const float* t_tw = (const float*)d_in[20];
  const float* t_tb = (const float*)d_in[21];

  const long long TBH = (long long)T_DIM * B_DIM * H_DIM;
  const long long BTN = (long long)B_DIM * T_DIM * N_DIM;
  const long long NBH = (long long)N_DIM * B_DIM * H_DIM;
  const long long WS  = (long long)H_DIM * H_DIM;

  float* out = (float*)d_out;
  float* out_v   = out;
  float* out_t   = out + TBH;
  float* out_vnm = out + 2 * TBH;
  float* out_tnm = out + 2 * TBH + BTN;
  float* out_vta = out + 2 * TBH + 2 * BTN;
  float* out_tta = out_vta + NT_DIM * B_DIM;

  char* w = (char*)d_ws;
  auto alloc = [&](long long bytes) {
    char* p = w; w += (bytes + 255) & ~255LL; return p;
  };
  short* WT   = (short*)alloc(8 * WS * 2);
  short* Qv   = (short*)alloc(TBH * 2);
  short* Qt   = (short*)alloc(TBH * 2);
  short* KVv  = (short*)alloc(2048LL * 1024 * 2);
  short* KVt  = (short*)alloc(2048LL * 1024 * 2);
  short* VWTv = (short*)alloc(NBH * 2);    // (V@Wo)^T per b: [b][h][n]
  short* VWTt = (short*)alloc(NBH * 2);
  short* Av   = (short*)alloc(BTN * 2);
  short* At   = (short*)alloc(BTN * 2);
  short* Lv   = (short*)alloc(BTN * 2);
  short* Lt   = (short*)alloc(BTN * 2);

  const float rsq = 0.044194173824159216f;  // 1/sqrt(512)

  // 1. weight transpose + cvt
  WSrc ws8;
  for (int i = 0; i < 8; ++i) ws8.p[i] = (const float*)d_in[8 + i];
  wtrans_kernel<<<dim3(16, 16, 8), dim3(32, 8), 0, stream>>>(ws8, WT);

  // 2. Q projections (f32 A), both domains
  {
    GP p = {{v_frame, t_frame}, {WT + 0 * WS, WT + 4 * WS}, {Qv, Qt}, {nullptr, nullptr}};
    gemm_tn<float, short, false><<<dim3(256, 4, 2), dim3(256), 0, stream>>>(
        p, 0, 0LL, H_DIM, 0LL, H_DIM, 0LL, H_DIM, 512, 1.f);
  }

  // 3. merged K|V projections (Wk^T,Wv^T adjacent in WT), both domains
  {
    GP p = {{v_action, t_action}, {WT + 1 * WS, WT + 5 * WS}, {KVv, KVt}, {nullptr, nullptr}};
    gemm_tn<float, short, false><<<dim3(16, 8, 2), dim3(256), 0, stream>>>(
        p, 0, 0LL, H_DIM, 0LL, H_DIM, 0LL, 1024, 512, 1.f);
  }

  // 4. VWT[b][h][n] = (V@Wo)^T  (replaces vtrans + folds Wo into V)
  //    C[h][n] = sum_f WoT[h,f] * V[n,f];  V rows at KV + (n*8+b)*1024 + 512
  {
    GP p = {{WT + 3 * WS, WT + 7 * WS}, {KVv + 512, KVt + 512}, {VWTv, VWTt},
            {nullptr, nullptr}};
    gemm_tn<short, short, false><<<dim3(4, 2, 16), dim3(256), 0, stream>>>(
        p, 3, 0LL, H_DIM, 1024LL, 8192, (long long)H_DIM * N_DIM, N_DIM, 512, 1.f);
  }

  // 5. logits (bf16 out) [B,T,N], both domains (z = dom*8 + b)
  {
    GP p = {{Qv, Qt}, {KVv, KVt}, {Lv, Lt}, {nullptr, nullptr}};
    gemm_tn<short, short, false><<<dim3(32, 2, 16), dim3(256), 0, stream>>>(
        p, 3, 512LL, B_DIM * H_DIM, 1024LL, 8192,
        (long long)T_DIM * N_DIM, N_DIM, 512, rsq);
  }

  // 6. fused combine + softmax + nomask-transpose (writes out_nm directly)
  softmax_fused<<<dim3(T_DIM / 16, B_DIM), dim3(256), 0, stream>>>(
      Lv, Lt, v_mask, t_mask, v_aw, t_aw, Av, At, out_vnm, out_tnm);

  // 7. out = attn @ VW + frame  (K=256; fuses old steps 7+8)
  {
    GP p = {{Av, At}, {VWTv, VWTt}, {out_v, out_t}, {v_frame, t_frame}};
    gemm_tn<short, float, true><<<dim3(32, 4, 16), dim3(256), 0, stream>>>(
        p, 3, (long long)T_DIM * N_DIM, N_DIM, (long long)H_DIM * N_DIM, N_DIM,
        512LL, B_DIM * H_DIM, 256, 1.f);
  }

  // 8. task heads
  task_kernel<<<dim3(1), dim3(1024), 0, stream>>>(
      v_task, t_task, v_tw, v_tb, t_tw, t_tb, out_vta, out_tta);
}